// Round 10
// baseline (313.871 us; speedup 1.0000x reference)
//
#include <hip/hip_runtime.h>
#include <math.h>

namespace {

constexpr int Bn = 16;    // batch
constexpr int NG = 1024;  // general tokens
constexpr int Cc = 768;   // channels
constexpr int Hh = 12;    // heads
constexpr int HD = 64;    // head dim
constexpr int Nn = 1026;  // total tokens (cls, box, general)
constexpr int NR = 18;    // rows we actually need: 0,1 + 16 routed
constexpr int NPK = 1152; // padded token count (9*128) for MFMA K / N tiles
constexpr int NCH = 16;   // c-chunks for k_rlogits (c-chunk = 48)

typedef __attribute__((ext_vector_type(8))) short short8;
typedef __attribute__((ext_vector_type(4))) float f32x4;

__device__ inline unsigned short f2bf(float f) {
  unsigned u = __float_as_uint(f);
  unsigned r = u + 0x7FFFu + ((u >> 16) & 1u);
  return (unsigned short)(r >> 16);
}

// ---------------- K1: LayerNorm (fp64 accumulation) ----------------
__global__ __launch_bounds__(256) void k_ln(
    const float* __restrict__ gen, const float* __restrict__ cls,
    const float* __restrict__ box, const float* __restrict__ gamma,
    const float* __restrict__ beta, float* __restrict__ x,
    unsigned short* __restrict__ xbf) {
  int blk = blockIdx.x;
  int b = blk / Nn, n = blk % Nn;
  const float* src = (n == 0) ? cls + (size_t)b * Cc
                   : (n == 1) ? box + (size_t)b * Cc
                              : gen + ((size_t)b * NG + (n - 2)) * Cc;
  int t = threadIdx.x;
  float v0 = src[t], v1 = src[t + 256], v2 = src[t + 512];
  __shared__ double red[8];
  double s = (double)v0 + (double)v1 + (double)v2;
  for (int o = 32; o > 0; o >>= 1) s += __shfl_down(s, o, 64);
  int wid = t >> 6, lid = t & 63;
  if (lid == 0) red[wid] = s;
  __syncthreads();
  if (t == 0) red[4] = (red[0] + red[1] + red[2] + red[3]) / Cc;
  __syncthreads();
  double mean = red[4];
  double d0 = (double)v0 - mean, d1 = (double)v1 - mean, d2 = (double)v2 - mean;
  double sq = d0 * d0 + d1 * d1 + d2 * d2;
  for (int o = 32; o > 0; o >>= 1) sq += __shfl_down(sq, o, 64);
  __syncthreads();
  if (lid == 0) red[wid] = sq;
  __syncthreads();
  if (t == 0) {
    double var = (red[0] + red[1] + red[2] + red[3]) / Cc;
    red[5] = 1.0 / sqrt(var + 1e-5);
  }
  __syncthreads();
  double rs = red[5];
  float* dst = x + ((size_t)b * Nn + n) * Cc;
  unsigned short* dbf = xbf + ((size_t)b * NPK + n) * Cc;
  float o0 = (float)(d0 * rs * (double)gamma[t]       + (double)beta[t]);
  float o1 = (float)(d1 * rs * (double)gamma[t + 256] + (double)beta[t + 256]);
  float o2 = (float)(d2 * rs * (double)gamma[t + 512] + (double)beta[t + 512]);
  dst[t] = o0; dst[t + 256] = o1; dst[t + 512] = o2;
  dbf[t] = f2bf(o0); dbf[t + 256] = f2bf(o1); dbf[t + 512] = f2bf(o2);
}

// ---------------- K1p: merged prep — padzero + wcvt + wkt ----------------
__global__ __launch_bounds__(256) void k_prep(
    const float* __restrict__ wqkv, const float* __restrict__ wproj,
    unsigned short* __restrict__ xbf, unsigned short* __restrict__ wqb,
    unsigned short* __restrict__ wvb, unsigned short* __restrict__ wpb,
    unsigned short* __restrict__ wkTb) {
  __shared__ unsigned short ts[64][72];
  int blk = blockIdx.x;
  int t = threadIdx.x;
  if (blk < 96) {
    constexpr int PERB = (NPK - Nn) * Cc / 2;  // uints per batch
    int idx = blk * 256 + t;
    int total = Bn * PERB;
    for (int i = idx; i < total; i += 96 * 256) {
      int b = i / PERB, r = i % PERB;
      unsigned int* p = (unsigned int*)(xbf + ((size_t)b * NPK + Nn) * Cc);
      p[r] = 0u;
    }
  } else if (blk < 672) {
    int i = ((blk - 96) * 256 + t) * 4;
    const float* wq = wqkv;
    const float* wv = wqkv + (size_t)2 * Cc * Cc;
    float4 q = *(const float4*)(wq + i);
    float4 a = *(const float4*)(wv + i);
    float4 b = *(const float4*)(wproj + i);
    ushort4 oq, oa, ob;
    oq.x = f2bf(q.x); oq.y = f2bf(q.y); oq.z = f2bf(q.z); oq.w = f2bf(q.w);
    oa.x = f2bf(a.x); oa.y = f2bf(a.y); oa.z = f2bf(a.z); oa.w = f2bf(a.w);
    ob.x = f2bf(b.x); ob.y = f2bf(b.y); ob.z = f2bf(b.z); ob.w = f2bf(b.w);
    *(ushort4*)(wqb + i) = oq;
    *(ushort4*)(wvb + i) = oa;
    *(ushort4*)(wpb + i) = ob;
  } else {
    int q = blk - 672;
    int rt = q / 12, ct = q % 12;
    const float* src = wqkv + (size_t)Cc * Cc;
    #pragma unroll
    for (int l = 0; l < 4; l++) {
      int idx = t + l * 256;
      int r = idx >> 4, c4 = idx & 15;
      float4 v = *(const float4*)(src + (size_t)(rt * 64 + r) * Cc + ct * 64 + c4 * 4);
      ts[r][c4 * 4 + 0] = f2bf(v.x); ts[r][c4 * 4 + 1] = f2bf(v.y);
      ts[r][c4 * 4 + 2] = f2bf(v.z); ts[r][c4 * 4 + 3] = f2bf(v.w);
    }
    __syncthreads();
    #pragma unroll
    for (int l = 0; l < 2; l++) {
      int idx = t + l * 256;
      int r2 = idx >> 3, j8 = idx & 7;
      unsigned short tmp[8];
      #pragma unroll
      for (int i = 0; i < 8; i++) tmp[i] = ts[j8 * 8 + i][r2];
      *(uint4*)(wkTb + (size_t)(ct * 64 + r2) * Cc + rt * 64 + j8 * 8) = *(uint4*)tmp;
    }
  }
}

// ---------------- K1c: transpose x_bf -> xT_bf [b][c][jpad] ----------------
__global__ __launch_bounds__(256) void k_xt(
    const unsigned short* __restrict__ xbf, unsigned short* __restrict__ xT) {
  int b = blockIdx.x, jt = blockIdx.y, ct = blockIdx.z;
  int j0 = jt * 64, c0 = ct * 64;
  __shared__ unsigned short ts[64][80];
  int t = threadIdx.x;
  #pragma unroll
  for (int l = 0; l < 2; l++) {
    int chunk = t + l * 256;
    int r = chunk >> 3, c8 = chunk & 7;
    uint4 v = *(const uint4*)(xbf + ((size_t)b * NPK + j0 + r) * Cc + c0 + c8 * 8);
    *(uint4*)&ts[r][c8 * 8] = v;
  }
  __syncthreads();
  #pragma unroll
  for (int l = 0; l < 2; l++) {
    int chunk = t + l * 256;
    int orow = chunk >> 3, j8 = chunk & 7;
    unsigned short tmp[8];
    #pragma unroll
    for (int i = 0; i < 8; i++) tmp[i] = ts[j8 * 8 + i][orow];
    *(uint4*)(xT + ((size_t)b * Cc + c0 + orow) * NPK + j0 + j8 * 8) = *(uint4*)tmp;
  }
}

// ---------------- K2: q rows 0,1 (fp64) — one wave per output ----------------
__global__ __launch_bounds__(256) void k_q01(
    const float* __restrict__ wqkv, const float* __restrict__ x,
    double* __restrict__ q01d) {
  int row = blockIdx.x;
  int b = row >> 1, i = row & 1;
  __shared__ float xl[Cc];
  const float* xr = x + ((size_t)b * Nn + i) * Cc;
  for (int c = threadIdx.x; c < Cc; c += 256) xl[c] = xr[c];
  __syncthreads();
  int w = threadIdx.x >> 6, lane = threadIdx.x & 63;
  int o = blockIdx.y * 4 + w;
  const float* wr = wqkv + (size_t)o * Cc + lane * 12;
  const float* xs = xl + lane * 12;
  double acc = 0;
  #pragma unroll
  for (int k = 0; k < 12; k++) acc += (double)wr[k] * (double)xs[k];
  for (int off = 32; off > 0; off >>= 1) acc += __shfl_down(acc, off, 64);
  if (lane == 0) q01d[(size_t)row * Cc + o] = acc;
}

// ---------------- K3: u rows 0,1 (fp64), c-split ----------------
__global__ __launch_bounds__(256) void k_u01(
    const float* __restrict__ wqkv, const double* __restrict__ q01d,
    double* __restrict__ u01d) {
  int blk = blockIdx.x;
  int h = blk % Hh; int i = (blk / Hh) & 1; int b = blk / (2 * Hh);
  __shared__ double qh[HD];
  const double* q = q01d + ((size_t)b * 2 + i) * Cc + h * HD;
  if (threadIdx.x < HD) qh[threadIdx.x] = q[threadIdx.x];
  __syncthreads();
  const float* wk = wqkv + (size_t)Cc * Cc;
  int c = blockIdx.y * 256 + threadIdx.x;
  double a0 = 0, a1 = 0, a2 = 0, a3 = 0;
  #pragma unroll 4
  for (int d = 0; d < HD; d += 4) {
    a0 += qh[d]     * (double)wk[(size_t)(h * HD + d) * Cc + c];
    a1 += qh[d + 1] * (double)wk[(size_t)(h * HD + d + 1) * Cc + c];
    a2 += qh[d + 2] * (double)wk[(size_t)(h * HD + d + 2) * Cc + c];
    a3 += qh[d + 3] * (double)wk[(size_t)(h * HD + d + 3) * Cc + c];
  }
  u01d[(((size_t)(b * 2 + i)) * Hh + h) * Cc + c] = (a0 + a1) + (a2 + a3);
}

// ---------------- K3b: logits for columns j=0,1 (fp64 dots) ----------------
__global__ __launch_bounds__(256) void k_r01(
    const double* __restrict__ u01d, const float* __restrict__ x,
    double* __restrict__ Ld01) {
  int b = blockIdx.x >> 1, i = blockIdx.x & 1;
  int w = threadIdx.x >> 6, lane = threadIdx.x & 63;
  for (int k = 0; k < 6; k++) {
    int p = w * 6 + k;
    int h = p >> 1, j = p & 1;
    const double* u = u01d + (((size_t)(b * 2 + i)) * Hh + h) * Cc;
    const float* xr = x + ((size_t)b * Nn + j) * Cc;
    double acc = 0;
    for (int c = lane; c < Cc; c += 64) acc += u[c] * (double)xr[c];
    for (int off = 32; off > 0; off >>= 1) acc += __shfl_down(acc, off, 64);
    if (lane == 0) Ld01[(((size_t)(b * 2 + i)) * Hh + h) * 2 + j] = acc * 0.125;
  }
}

// ---------------- K4: routing logits, general tokens (fp64, JT=8) ----------
__global__ __launch_bounds__(256) void k_rlogits(
    const double* __restrict__ u01d, const float* __restrict__ x,
    float* __restrict__ Ldp) {
  int b = blockIdx.x, jt = blockIdx.y, cch = blockIdx.z;
  int c0 = cch * 48;
  int t = threadIdx.x;
  int w = t >> 6, lane = t & 63;
  int g = w >> 1;
  int hh = (w & 1) * 6;
  __shared__ double ut[24][48];
  __shared__ __align__(16) float xtT[16][516];
  for (int idx = t; idx < 24 * 48; idx += 256) {
    int row = idx / 48, cc = idx % 48;
    int ig = row / 12, hr = row % 12;
    ut[row][cc] = u01d[(((size_t)(b * 2 + ig)) * Hh + hr) * Cc + c0 + cc];
  }
  double acc[6][8] = {};
  for (int s = 0; s < 3; s++) {
    #pragma unroll
    for (int l = 0; l < 8; l++) {
      int idx = t + l * 256;
      int row = idx >> 2, c4 = idx & 3;
      const float* xr = x + ((size_t)b * Nn + 2 + jt * 512 + row) * Cc + c0 + s * 16 + c4 * 4;
      float4 v = *(const float4*)xr;
      xtT[c4 * 4 + 0][row] = v.x;
      xtT[c4 * 4 + 1][row] = v.y;
      xtT[c4 * 4 + 2][row] = v.z;
      xtT[c4 * 4 + 3][row] = v.w;
    }
    __syncthreads();
    for (int cc = 0; cc < 16; cc++) {
      float4 xa = *(const float4*)&xtT[cc][lane * 8];
      float4 xb = *(const float4*)&xtT[cc][lane * 8 + 4];
      double x0 = (double)xa.x, x1 = (double)xa.y, x2 = (double)xa.z, x3 = (double)xa.w;
      double x4 = (double)xb.x, x5 = (double)xb.y, x6 = (double)xb.z, x7 = (double)xb.w;
      #pragma unroll
      for (int r = 0; r < 6; r++) {
        double uv = ut[g * 12 + hh + r][s * 16 + cc];
        acc[r][0] += uv * x0; acc[r][1] += uv * x1;
        acc[r][2] += uv * x2; acc[r][3] += uv * x3;
        acc[r][4] += uv * x4; acc[r][5] += uv * x5;
        acc[r][6] += uv * x6; acc[r][7] += uv * x7;
      }
    }
    __syncthreads();
  }
  for (int r = 0; r < 6; r++) {
    int rowo = g * 12 + hh + r;
    float4 o0, o1;
    o0.x = (float)(acc[r][0] * 0.125); o0.y = (float)(acc[r][1] * 0.125);
    o0.z = (float)(acc[r][2] * 0.125); o0.w = (float)(acc[r][3] * 0.125);
    o1.x = (float)(acc[r][4] * 0.125); o1.y = (float)(acc[r][5] * 0.125);
    o1.z = (float)(acc[r][6] * 0.125); o1.w = (float)(acc[r][7] * 0.125);
    size_t base = (((size_t)cch * Bn + b) * 24 + rowo) * 1024 + jt * 512 + lane * 8;
    *(float4*)&Ldp[base] = o0;
    *(float4*)&Ldp[base + 4] = o1;
  }
}

// ---------------- K5: sum partials + mask + softmax (fp64) ----------------
__global__ __launch_bounds__(256) void k_rsoftmax(
    const float* __restrict__ Ldp, const double* __restrict__ Ld01,
    double* __restrict__ Ld, unsigned short* __restrict__ Pb) {
  int blk = blockIdx.x;
  int h = blk % Hh; int i = (blk / Hh) & 1; int b = blk / (2 * Hh);
  double* row = Ld + (size_t)blk * Nn;
  unsigned short* prow = Pb + ((size_t)b * 216 + i * Hh + h) * NPK;
  int t = threadIdx.x;
  size_t poff = ((size_t)b * 24 + i * 12 + h) * 1024;
  constexpr size_t PSTRIDE = (size_t)Bn * 24 * 1024;
  double lv[5];
  int cnt = 0;
  double mx = -1e300;
  for (int j = t; j < Nn; j += 256) {
    double L;
    if (j < 2) {
      L = Ld01[(((size_t)(b * 2 + i)) * Hh + h) * 2 + j];
      if (i == 0 && j == 1) L = 0.0;
      if (i == 1 && j == 0) L = 0.0;
    } else {
      L = 0;
      #pragma unroll
      for (int p = 0; p < NCH; p++) L += (double)Ldp[(size_t)p * PSTRIDE + poff + (j - 2)];
    }
    lv[cnt++] = L;
    mx = fmax(mx, L);
  }
  __shared__ double sd[256];
  sd[t] = mx; __syncthreads();
  for (int st = 128; st > 0; st >>= 1) { if (t < st) sd[t] = fmax(sd[t], sd[t + st]); __syncthreads(); }
  mx = sd[0]; __syncthreads();
  double sum = 0;
  for (int k = 0; k < cnt; k++) { lv[k] = exp(lv[k] - mx); sum += lv[k]; }
  sd[t] = sum; __syncthreads();
  for (int st = 128; st > 0; st >>= 1) { if (t < st) sd[t] += sd[t + st]; __syncthreads(); }
  double inv = 1.0 / sd[0];
  int k = 0;
  for (int j = t; j < Nn; j += 256) {
    double p = lv[k++] * inv;
    row[j] = p;
    prow[j] = f2bf((float)p);
  }
  for (int j = Nn + t; j < NPK; j += 256) prow[j] = 0;
}

// ---------------- K6: head means -> sum_a, diff (fp64) ----------------
__global__ __launch_bounds__(256) void k_rsums(
    const double* __restrict__ Ld, double* __restrict__ suma,
    double* __restrict__ diffd) {
  int b = blockIdx.x;
  for (int jg = threadIdx.x; jg < NG; jg += 256) {
    int j = jg + 2;
    double cs = 0, bs = 0;
    for (int h = 0; h < Hh; h++) {
      cs += Ld[(((size_t)(b * 2 + 0)) * Hh + h) * Nn + j];
      bs += Ld[(((size_t)(b * 2 + 1)) * Hh + h) * Nn + j];
    }
    cs /= 12.0; bs /= 12.0;
    suma[(size_t)b * NG + jg] = cs + bs;
    diffd[(size_t)b * NG + jg] = bs - cs;
  }
}

// ---------------- K7: routing — both cats concurrent, shuffle argmax -------
__global__ __launch_bounds__(256) void k_route(
    const double* __restrict__ suma, const double* __restrict__ diffd,
    int* __restrict__ rowcat) {
  int b = blockIdx.x, t = threadIdx.x;
  __shared__ double vals[NG];
  __shared__ unsigned char flags[NG];
  __shared__ double redv[4];
  __shared__ int redi[4];
  __shared__ int blist[16], clist[16];
  __shared__ double blv[16], clv[16];
  for (int j = t; j < NG; j += 256) {
    vals[j] = suma[(size_t)b * NG + j];
    flags[j] = diffd[(size_t)b * NG + j] > 0.0 ? 1 : 0;
  }
  __syncthreads();
  int half = t >> 7;
  int lt = t & 127;
  int wv = t >> 6;
  int lane = t & 63;
  for (int s = 0; s < 16; s++) {
    double bv = -1e300; int bi = 0x7fffffff;
    #pragma unroll
    for (int k = 0; k < 8; k++) {
      int j = lt * 8 + k;
      double v = vals[j];
      if (flags[j] == half && v > bv) { bv = v; bi = j; }
    }
    for (int off = 32; off > 0; off >>= 1) {
      double ov = __shfl_down(bv, off, 64);
      int oi = __shfl_down(bi, off, 64);
      if (ov > bv || (ov == bv && oi < bi)) { bv = ov; bi = oi; }
    }
    if (lane == 0) { redv[wv] = bv; redi[wv] = bi; }
    __syncthreads();
    if (lt == 0) {
      double v0 = redv[half * 2], v1 = redv[half * 2 + 1];
      int i0 = redi[half * 2], i1 = redi[half * 2 + 1];
      if (v1 > v0 || (v1 == v0 && i1 < i0)) { v0 = v1; i0 = i1; }
      int win = (v0 > -1e299) ? i0 : -1;
      if (half) { blist[s] = win; blv[s] = v0; }
      else      { clist[s] = win; clv[s] = v0; }
      if (win >= 0) vals[win] = -1e300;
    }
    __syncthreads();
  }
  if (t < 16) {
    int s = t;
    int bc = blist[s];
    int cl = clist[15 - s];
    double bvv = blv[s], cvv = clv[15 - s];
    int win;
    if (bc < 0 && cl < 0) win = -1;
    else if (bc < 0) win = cl;
    else if (cl < 0) win = bc;
    else {
      bool boxwins = (bvv < cvv) || (bvv == cvv && bc > cl);
      win = boxwins ? bc : cl;
    }
    int tok = (win >= 0) ? win : 0;
    rowcat[b * NR + 2 + s] = tok + 2;
  }
  if (t == 0) { rowcat[b * NR + 0] = 0; rowcat[b * NR + 1] = 1; }
}

// ---------------- K8: q for 16 gathered rows via MFMA ----------------
__global__ __launch_bounds__(256) void k_qg_mfma(
    const unsigned short* __restrict__ xbf, const unsigned short* __restrict__ wqb,
    const int* __restrict__ rowcat, unsigned short* __restrict__ qb) {
  int mt = blockIdx.x, ng = blockIdx.y;
  int wid = threadIdx.x >> 6, lane = threadIdx.x & 63;
  int nt = ng * 4 + wid;
  int m = lane & 15, kg = lane >> 4;
  int rowi = mt * 16 + m;
  int b = rowi >> 4, s = rowi & 15;
  int tok = rowcat[b * NR + 2 + s];
  const unsigned short* abase = xbf + ((size_t)b * NPK + tok) * Cc + kg * 8;
  const unsigned short* bbase = wqb + (size_t)(nt * 16 + m) * Cc + kg * 8;
  f32x4 acc = {0, 0, 0, 0};
  for (int k0 = 0; k0 < Cc; k0 += 32) {
    short8 a = *(const short8*)(abase + k0);
    short8 bf = *(const short8*)(bbase + k0);
    acc = __builtin_amdgcn_mfma_f32_16x16x32_bf16(a, bf, acc, 0, 0, 0);
  }
  int c = nt * 16 + m;
  #pragma unroll
  for (int r = 0; r < 4; r++) {
    int rowo = mt * 16 + kg * 4 + r;
    qb[(size_t)rowo * Cc + c] = f2bf(acc[r]);
  }
}

// ---------------- K9: u for gathered rows via MFMA ----------------
__global__ __launch_bounds__(256) void k_ug_mfma(
    const unsigned short* __restrict__ qb, const unsigned short* __restrict__ wkTb,
    unsigned short* __restrict__ u16b) {
  int h = blockIdx.x, mt = blockIdx.y, ngz = blockIdx.z;
  int wid = threadIdx.x >> 6, lane = threadIdx.x & 63;
  int m = lane & 15, kg = lane >> 4;
  int rowi = mt * 16 + m;
  const unsigned short* abase = qb + (size_t)rowi * Cc + h * HD + kg * 8;
  f32x4 acc[4] = {{0,0,0,0},{0,0,0,0},{0,0,0,0},{0,0,0,0}};
  #pragma unroll
  for (int k0 = 0; k0 < HD; k0 += 32) {
    short8 a = *(const short8*)(abase + k0);
    #pragma unroll
    for (int t = 0; t < 4; t++) {
      int c = ngz * 256 + (wid * 4 + t) * 16 + m;
      short8 bf = *(const short8*)(wkTb + (size_t)c * Cc + h * HD + kg * 8 + k0);
      acc[t] = __builtin_amdgcn_mfma_f32_16x16x32_bf16(a, bf, acc[t], 0, 0, 0);
    }
  }
  #pragma unroll
  for (int t = 0; t < 4; t++) {
    int c = ngz * 256 + (wid * 4 + t) * 16 + m;
    #pragma unroll
    for (int r = 0; r < 4; r++) {
      int row = mt * 16 + kg * 4 + r;
      int b = row >> 4, s = row & 15;
      u16b[((size_t)b * 192 + s * Hh + h) * Cc + c] = f2bf(acc[t][r]);
    }
  }
}

// ---------------- K10: gathered logits — 2-wave blocks, 4m x 4n per wave ----
// grid (Bn, 3, 9): b, mg (64 rows), nz (128 cols). Per K-step per wave:
// 16 MFMA vs 4 ds_read_b128 + 4 global A loads (b-reads/MFMA = 0.25).
__global__ __launch_bounds__(128) void k_glogits_mfma(
    const unsigned short* __restrict__ u16b, const unsigned short* __restrict__ xbf,
    float* __restrict__ S) {
  int b = blockIdx.x, mg = blockIdx.y, nz = blockIdx.z;
  __shared__ __align__(16) unsigned short Bs[2][128 * 32];
  int t = threadIdx.x, w = t >> 6, lane = t & 63;
  int m = lane & 15, kg = lane >> 4;
  const unsigned short* ap[4];
  #pragma unroll
  for (int mt = 0; mt < 4; mt++)
    ap[mt] = u16b + ((size_t)b * 192 + mg * 64 + mt * 16 + m) * Cc + kg * 8;
  const unsigned short* gB[4];
  int lofs[4];
  #pragma unroll
  for (int l = 0; l < 4; l++) {
    int chunk = l * 128 + t;
    int col = chunk >> 2, kq = chunk & 3;
    gB[l] = xbf + ((size_t)b * NPK + nz * 128 + col) * Cc + kq * 8;
    lofs[l] = col * 32 + kq * 8;
  }
  constexpr int NIT = Cc / 32;  // 24
  #pragma unroll
  for (int l = 0; l < 4; l++) *(short8*)&Bs[0][lofs[l]] = *(const short8*)gB[l];
  __syncthreads();
  f32x4 acc[4][4] = {};
  for (int it = 0; it < NIT; it++) {
    int k0 = it * 32;
    int cur = it & 1;
    short8 nx[4];
    if (it + 1 < NIT) {
      #pragma unroll
      for (int l = 0; l < 4; l++) nx[l] = *(const short8*)(gB[l] + k0 + 32);
    }
    short8 a[4];
    #pragma unroll
    for (int mt = 0; mt < 4; mt++) a[mt] = *(const short8*)(ap[mt] + k0);
    #pragma unroll
    for (int tt = 0; tt < 4; tt++) {
      int col = w * 64 + tt * 16 + m;
      short8 bf = *(const short8*)&Bs[cur][col * 32 + kg * 8];
      #pragma unroll
      for (int mt = 0; mt < 4; mt++)
        acc[mt][tt] = __builtin_amdgcn_mfma_f32_16x16x32_bf16(a[mt], bf, acc[mt][tt], 0, 0, 0);
    }
    if (it + 1 < NIT) {
      #pragma unroll
      for (int l = 0; l < 4; l++) *(short8*)&Bs[cur ^ 1][lofs[l]] = nx[l];
    }
    __syncthreads();
  }
  #pragma unroll
  for (int mt = 0; mt < 4; mt++) {
    #pragma unroll
    for (int tt = 0; tt < 4; tt++) {
      int col = nz * 128 + w * 64 + tt * 16 + m;
      #pragma unroll
      for (int r = 0; r < 4; r++) {
        int row = mg * 64 + mt * 16 + kg * 4 + r;
        S[((size_t)b * 192 + row) * NPK + col] = acc[mt][tt][r] * 0.125f;
      }
    }
  }
}

// ---------------- K11: softmax for gathered rows (reads S, writes bf16 P) --
__global__ __launch_bounds__(256) void k_gsoftmax(
    const float* __restrict__ S, unsigned short* __restrict__ Pb) {
  int blk = blockIdx.x;
  int b = blk / 192, r = blk % 192;
  const float* row = S + ((size_t)b * 192 + r) * NPK;
  unsigned short* prow = Pb + ((size_t)b * 216 + 24 + r) * NPK;
  int t = threadIdx.x;
  __shared__ float sd[256];
  float mx = -1e30f;
  for (int j = t; j < Nn; j += 256) mx = fmaxf(mx, row[j]);
  sd[t] = mx; __syncthreads();
  for (int st = 128; st > 0; st >>= 1) { if (t < st) sd[t] = fmaxf(sd[t], sd[t + st]); __syncthreads(); }
  mx = sd[0]; __syncthreads();
  float sum = 0;
  for (int j = t; j < Nn; j += 256) sum += __expf(row[j] - mx);
  sd[t] = sum; __syncthreads();
  for (int st = 128; st > 0; st >>= 1) { if (t < st) sd[t] += sd[t + st]; __syncthreads(); }
  float inv = 1.0f / sd[0];
  for (int j = t; j < NPK; j += 256) {
    prow[j] = (j < Nn) ? f2bf(__expf(row[j] - mx) * inv) : (unsigned short)0;
  }
}

// ---------------- K12: wsum — 2-wave blocks, 4m x 4n per wave ----------------
// grid (Bn, 4, 6): b, mg (64 rows of 216+pad), nz (128 c-cols).
__global__ __launch_bounds__(128) void k_wsum_mfma(
    const unsigned short* __restrict__ Pb, const unsigned short* __restrict__ xT,
    unsigned short* __restrict__ wsumb) {
  int b = blockIdx.x, mg = blockIdx.y, nz = blockIdx.z;
  __shared__ __align__(16) unsigned short Bs[2][128 * 32];
  int t = threadIdx.x, w = t >> 6, lane = t & 63;
  int m = lane & 15, kg = lane >> 4;
  const unsigned short* ap[4];
  #pragma unroll
  for (int mt = 0; mt < 4; mt++) {
    int r = mg * 64 + mt * 16 + m;
    int rc = r < 216 ? r : 215;
    ap[mt] = Pb + ((size_t)b * 216 + rc) * NPK + kg * 8;
  }
  const unsigned short* gB[4];
  int lofs[4];
  #pragma unroll
  for (int l = 0; l < 4; l++) {
    int chunk = l * 128 + t;
    int col = chunk >> 2, kq = chunk & 3;
    gB[l] = xT + ((size_t)b * Cc + nz * 128 + col) * NPK + kq * 8;
    lofs[l] = col * 32 + kq * 8;
  }
  constexpr int NIT = NPK / 32;  // 36
  #pragma unroll
  for (int l = 0; l < 4; l++) *(short8*)&Bs[0][lofs[l]] = *(const short8*)gB[l];
  __syncthreads();
  f32x4 acc[4][4] = {};
  for (int it = 0; it < NIT; it++) {
    int k0 = it * 32;
    int cur = it & 1;
    short8 nx[4];
    if (it + 1 < NIT) {
      #pragma unroll
      for (int l = 0; l < 4; l++) nx[l] = *(const short8*)(gB[l] + k0 + 32);
    }
    short8 a[4];
    #pragma unroll
    for (int mt = 0; mt < 4; mt++) a[mt] = *(const short8*)(ap[mt] + k0);
    #pragma unroll
    for (int tt = 0; tt < 4; tt++) {
      int col = w * 64 + tt * 16 + m;
      short8 bf = *(const short8*)&Bs[cur][col * 32 + kg * 8];
      #pragma unroll
      for (int mt = 0; mt < 4; mt++)
        acc[mt][tt] = __builtin_amdgcn_mfma_f32_16x16x32_bf16(a[mt], bf, acc[mt][tt], 0, 0, 0);
    }
    if (it + 1 < NIT) {
      #pragma unroll
      for (int l = 0; l < 4; l++) *(short8*)&Bs[cur ^ 1][lofs[l]] = nx[l];
    }
    __syncthreads();
  }
  #pragma unroll
  for (int mt = 0; mt < 4; mt++) {
    #pragma unroll
    for (int tt = 0; tt < 4; tt++) {
      int col = nz * 128 + w * 64 + tt * 16 + m;
      #pragma unroll
      for (int r = 0; r < 4; r++) {
        int row = mg * 64 + mt * 16 + kg * 4 + r;
        if (row < 216) wsumb[((size_t)b * 216 + row) * Cc + col] = f2bf(acc[mt][tt][r]);
      }
    }
  }
}

// ---------------- K13: attnout = Wv * wsum via MFMA ----------------
__global__ __launch_bounds__(256) void k_attnout_mfma(
    const unsigned short* __restrict__ wsumb, const unsigned short* __restrict__ wvb,
    unsigned short* __restrict__ aob) {
  int h = blockIdx.x, mt = blockIdx.y;
  int wid = threadIdx.x >> 6, lane = threadIdx.x & 63;
  int m = lane & 15, kg = lane >> 4;
  int row = mt * 16 + m;
  int b = row / NR, i = row % NR;
  const unsigned short* abase = wsumb + ((size_t)b * 216 + i * 12 + h) * Cc + kg * 8;
  const unsigned short* bbase = wvb + (size_t)(h * HD + wid * 16 + m) * Cc + kg * 8;
  f32x4 acc = {0, 0, 0, 0};
  for (int k0 = 0; k0 < Cc; k0 += 32) {
    short8 a = *(const short8*)(abase + k0);
    short8 bf = *(const short8*)(bbase + k0);
    acc = __builtin_amdgcn_mfma_f32_16x16x32_bf16(a, bf, acc, 0, 0, 0);
  }
  #pragma unroll
  for (int r = 0; r < 4; r++) {
    int orow = mt * 16 + kg * 4 + r;
    int ocol = h * HD + wid * 16 + m;
    aob[(size_t)orow * Cc + ocol] = f2bf(acc[r]);
  }
}

// ---------------- K14: proj via MFMA + bias + residual + scatter ----------
__global__ __launch_bounds__(256) void k_proj_mfma(
    const unsigned short* __restrict__ aob, const unsigned short* __restrict__ wpb,
    const float* __restrict__ bproj, const int* __restrict__ rowcat,
    const float* __restrict__ gen, const float* __restrict__ cls,
    const float* __restrict__ box, float* __restrict__ out) {
  int mt = blockIdx.x, ng = blockIdx.y;
  int wid = threadIdx.x >> 6, lane = threadIdx.x & 63;
  int nt = ng * 4 + wid;
  int m = lane & 15, kg = lane >> 4;
  const unsigned short* abase = aob + (size_t)(mt * 16 + m) * Cc + kg * 8;
  const unsigned short* bbase = wpb + (size_t)(nt * 16 + m) * Cc + kg * 8;
  f32x4 acc = {0, 0, 0, 0};
  for (int k0 = 0; k0 < Cc; k0 += 32) {
    short8 a = *(const short8*)(abase + k0);
    short8 bf = *(const short8*)(bbase + k0);
    acc = __builtin_amdgcn_mfma_f32_16x16x32_bf16(a, bf, acc, 0, 0, 0);
  }
  int c = nt * 16 + m;
  float bp = bproj[c];
  #pragma unroll
  for (int r = 0; r < 4; r++) {
    int bi = mt * 16 + kg * 4 + r;
    int b = bi / NR, i = bi % NR;
    int tok = rowcat[b * NR + i];
    const float* src = (tok == 0) ? cls + (size_t)b * Cc
                     : (tok == 1) ? box + (size_t)b * Cc
                                  : gen + ((size_t)b * NG + tok - 2) * Cc;
    float val = acc[r] + bp + src[c];
    float* dst;
    if (i == 0)       dst = out + ((size_t)b * 9 + 0) * Cc;
    else if (i == 1)  dst = out + (size_t)Bn * 9 * Cc + ((size_t)b * 9 + 0) * Cc;
    else if (i < 10)  dst = out + ((size_t)b * 9 + (i - 1)) * Cc;
    else              dst = out + (size_t)Bn * 9 * Cc + ((size_t)b * 9 + (i - 9)) * Cc;
    dst[c] = val;
  }
}

}  // namespace

extern "C" void kernel_launch(void* const* d_in, const int* in_sizes, int n_in,
                              void* d_out, int out_size, void* d_ws, size_t ws_size,
                              hipStream_t stream) {
  (void)in_sizes; (void)n_in; (void)out_size; (void)ws_size;
  const float* gen   = (const float*)d_in[0];
  const float* cls   = (const float*)d_in[1];
  const float* box   = (const float*)d_in[2];
  const float* wqkv  = (const float*)d_in[3];
  const float* wproj = (const float*)d_in[4];
  const float* bproj = (const float*)d_in[5];
  const float* gamma = (const float*)d_in[6];
  const float* beta  = (const float*)d_in[7];
  float* out = (float*)d_out;

  char* ws = (char*)d_ws;
  size_t off = 0;
  auto alloc = [&](size_t bytes) { void* p = ws + off; off += (bytes + 255) & ~(size_t)255; return p; };
  float* x             = (float*)alloc((size_t)Bn * Nn * Cc * 4);
  unsigned short* xbf  = (unsigned short*)alloc((size_t)Bn * NPK * Cc * 2);
  unsigned short* xT   = (unsigned short*)alloc((size_t)Bn * Cc * NPK * 2);
  unsigned short* qb   = (unsigned short*)alloc((size_t)256 * Cc * 2);
  unsigned short* u16b = (unsigned short*)alloc((size_t)Bn * 192 * Cc * 2);
  float* S             = (float*)alloc((size_t)Bn * 192 * NPK * 4);
  unsigned short* Pb   = (unsigned short*)alloc((size_t)Bn * 216 * NPK * 2);
  unsigned short* wsumb= (unsigned short*)alloc((size_t)Bn * 216 * Cc * 2);
  unsigned short* aob  = (unsigned short*)alloc((size_t)288 * Cc * 2);
  unsigned short* wqb  = (unsigned short*)alloc((size_t)Cc * Cc * 2);
  unsigned short* wvb  = (unsigned short*)alloc((size_t)Cc * Cc * 2);
  unsigned short* wpb  = (unsigned short*)alloc((size_t)Cc * Cc * 2);
  unsigned short* wkTb = (unsigned short*)alloc((size_t)Cc * Cc * 2);
  double* q01d         = (double*)alloc((size_t)Bn * 2 * Cc * 8);
  double* u01d         = (double*)alloc((size_t)Bn * 2 * Hh * Cc * 8);
  double* Ld           = (double*)alloc((size_t)Bn * 2 * Hh * Nn * 8);
  double* Ld01         = (double*)alloc((size_t)Bn * 2 * Hh * 2 * 8);
  float* Ldp           = (float*)alloc((size_t)NCH * Bn * 24 * 1024 * 4);
  double* suma         = (double*)alloc((size_t)Bn * NG * 8);
  double* diffd        = (double*)alloc((size_t)Bn * NG * 8);
  int* rowcat          = (int*)alloc((size_t)Bn * NR * 4);

  k_ln<<<Bn * Nn, 256, 0, stream>>>(gen, cls, box, gamma, beta, x, xbf);
  k_prep<<<816, 256, 0, stream>>>(wqkv, wproj, xbf, wqb, wvb, wpb, wkTb);
  k_xt<<<dim3(Bn, NPK / 64, Cc / 64), 256, 0, stream>>>(xbf, xT);
  k_q01<<<dim3(Bn * 2, 192), 256, 0, stream>>>(wqkv, x, q01d);
  k_u01<<<dim3(Bn * 2 * Hh, 3), 256, 0, stream>>>(wqkv, q01d, u01d);
  k_r01<<<Bn * 2, 256, 0, stream>>>(u01d, x, Ld01);
  k_rlogits<<<dim3(Bn, 2, NCH), 256, 0, stream>>>(u01d, x, Ldp);
  k_rsoftmax<<<Bn * 2 * Hh, 256, 0, stream>>>(Ldp, Ld01, Ld, Pb);
  k_rsums<<<Bn, 256, 0, stream>>>(Ld, suma, diffd);
  k_route<<<Bn, 256, 0, stream>>>(suma, diffd, rowcat);
  k_qg_mfma<<<dim3(16, 12), 256, 0, stream>>>(xbf, wqb, rowcat, qb);
  k_ug_mfma<<<dim3(Hh, 16, 3), 256, 0, stream>>>(qb, wkTb, u16b);
  k_glogits_mfma<<<dim3(Bn, 3, 9), 128, 0, stream>>>(u16b, xbf, S);
  k_gsoftmax<<<Bn * 192, 256, 0, stream>>>(S, Pb);
  k_wsum_mfma<<<dim3(Bn, 4, 6), 128, 0, stream>>>(Pb, xT, wsumb);
  k_attnout_mfma<<<dim3(Hh, 18), 256, 0, stream>>>(wsumb, wvb, aob);
  k_proj_mfma<<<dim3(18, 12), 256, 0, stream>>>(aob, wpb, bproj, rowcat, gen, cls, box, out);
}

// Round 11
// 298.682 us; speedup vs baseline: 1.0509x; 1.0509x over previous
//
#include <hip/hip_runtime.h>
#include <math.h>

namespace {

constexpr int Bn = 16;    // batch
constexpr int NG = 1024;  // general tokens
constexpr int Cc = 768;   // channels
constexpr int Hh = 12;    // heads
constexpr int HD = 64;    // head dim
constexpr int Nn = 1026;  // total tokens (cls, box, general)
constexpr int NR = 18;    // rows we actually need: 0,1 + 16 routed
constexpr int NPK = 1152; // padded token count (9*128) for MFMA K / N tiles
constexpr int NCH = 16;   // c-chunks for k_rlogits (c-chunk = 48)

typedef __attribute__((ext_vector_type(8))) short short8;
typedef __attribute__((ext_vector_type(4))) float f32x4;

__device__ inline unsigned short f2bf(float f) {
  unsigned u = __float_as_uint(f);
  unsigned r = u + 0x7FFFu + ((u >> 16) & 1u);
  return (unsigned short)(r >> 16);
}

// ---------------- K1: LayerNorm (fp64 accumulation) + xbf pad-zero ---------
// blocks [0, Bn*Nn): LN rows; blocks [Bn*Nn, Bn*Nn+96): zero-pad xbf rows.
__global__ __launch_bounds__(256) void k_ln(
    const float* __restrict__ gen, const float* __restrict__ cls,
    const float* __restrict__ box, const float* __restrict__ gamma,
    const float* __restrict__ beta, float* __restrict__ x,
    unsigned short* __restrict__ xbf) {
  int blk = blockIdx.x;
  int t = threadIdx.x;
  if (blk >= Bn * Nn) {
    constexpr int PERB = (NPK - Nn) * Cc / 2;  // uints per batch
    int idx = (blk - Bn * Nn) * 256 + t;
    int total = Bn * PERB;
    for (int i = idx; i < total; i += 96 * 256) {
      int b = i / PERB, r = i % PERB;
      unsigned int* p = (unsigned int*)(xbf + ((size_t)b * NPK + Nn) * Cc);
      p[r] = 0u;
    }
    return;
  }
  int b = blk / Nn, n = blk % Nn;
  const float* src = (n == 0) ? cls + (size_t)b * Cc
                   : (n == 1) ? box + (size_t)b * Cc
                              : gen + ((size_t)b * NG + (n - 2)) * Cc;
  float v0 = src[t], v1 = src[t + 256], v2 = src[t + 512];
  __shared__ double red[8];
  double s = (double)v0 + (double)v1 + (double)v2;
  for (int o = 32; o > 0; o >>= 1) s += __shfl_down(s, o, 64);
  int wid = t >> 6, lid = t & 63;
  if (lid == 0) red[wid] = s;
  __syncthreads();
  if (t == 0) red[4] = (red[0] + red[1] + red[2] + red[3]) / Cc;
  __syncthreads();
  double mean = red[4];
  double d0 = (double)v0 - mean, d1 = (double)v1 - mean, d2 = (double)v2 - mean;
  double sq = d0 * d0 + d1 * d1 + d2 * d2;
  for (int o = 32; o > 0; o >>= 1) sq += __shfl_down(sq, o, 64);
  __syncthreads();
  if (lid == 0) red[wid] = sq;
  __syncthreads();
  if (t == 0) {
    double var = (red[0] + red[1] + red[2] + red[3]) / Cc;
    red[5] = 1.0 / sqrt(var + 1e-5);
  }
  __syncthreads();
  double rs = red[5];
  float* dst = x + ((size_t)b * Nn + n) * Cc;
  unsigned short* dbf = xbf + ((size_t)b * NPK + n) * Cc;
  float o0 = (float)(d0 * rs * (double)gamma[t]       + (double)beta[t]);
  float o1 = (float)(d1 * rs * (double)gamma[t + 256] + (double)beta[t + 256]);
  float o2 = (float)(d2 * rs * (double)gamma[t + 512] + (double)beta[t + 512]);
  dst[t] = o0; dst[t + 256] = o1; dst[t + 512] = o2;
  dbf[t] = f2bf(o0); dbf[t + 256] = f2bf(o1); dbf[t + 512] = f2bf(o2);
}

// ---------------- K2 mega1: xt (3456) + wcvt (576) + wkt (144) + q01 (6144)
// All depend only on k_ln outputs / raw weights; packed into one launch.
__global__ __launch_bounds__(256) void k_mega1(
    const unsigned short* __restrict__ xbf, unsigned short* __restrict__ xT,
    const float* __restrict__ wqkv, const float* __restrict__ wproj,
    unsigned short* __restrict__ wqb, unsigned short* __restrict__ wvb,
    unsigned short* __restrict__ wpb, unsigned short* __restrict__ wkTb,
    const float* __restrict__ x, double* __restrict__ q01d) {
  __shared__ __align__(16) char smem[64 * 80 * 2];
  int blk = blockIdx.x;
  int t = threadIdx.x;
  if (blk < 3456) {
    // ---- transpose x_bf -> xT_bf [b][c][jpad] ----
    int b = blk / 216, rem = blk % 216;
    int jt = rem / 12, ct = rem % 12;
    int j0 = jt * 64, c0 = ct * 64;
    auto ts = (unsigned short(*)[80])smem;
    #pragma unroll
    for (int l = 0; l < 2; l++) {
      int chunk = t + l * 256;
      int r = chunk >> 3, c8 = chunk & 7;
      uint4 v = *(const uint4*)(xbf + ((size_t)b * NPK + j0 + r) * Cc + c0 + c8 * 8);
      *(uint4*)&ts[r][c8 * 8] = v;
    }
    __syncthreads();
    #pragma unroll
    for (int l = 0; l < 2; l++) {
      int chunk = t + l * 256;
      int orow = chunk >> 3, j8 = chunk & 7;
      unsigned short tmp[8];
      #pragma unroll
      for (int i = 0; i < 8; i++) tmp[i] = ts[j8 * 8 + i][orow];
      *(uint4*)(xT + ((size_t)b * Cc + c0 + orow) * NPK + j0 + j8 * 8) = *(uint4*)tmp;
    }
  } else if (blk < 4032) {
    // ---- convert Wq, Wv, Wproj to bf16 ----
    int i = ((blk - 3456) * 256 + t) * 4;
    const float* wq = wqkv;
    const float* wv = wqkv + (size_t)2 * Cc * Cc;
    float4 q = *(const float4*)(wq + i);
    float4 a = *(const float4*)(wv + i);
    float4 b = *(const float4*)(wproj + i);
    ushort4 oq, oa, ob;
    oq.x = f2bf(q.x); oq.y = f2bf(q.y); oq.z = f2bf(q.z); oq.w = f2bf(q.w);
    oa.x = f2bf(a.x); oa.y = f2bf(a.y); oa.z = f2bf(a.z); oa.w = f2bf(a.w);
    ob.x = f2bf(b.x); ob.y = f2bf(b.y); ob.z = f2bf(b.z); ob.w = f2bf(b.w);
    *(ushort4*)(wqb + i) = oq;
    *(ushort4*)(wvb + i) = oa;
    *(ushort4*)(wpb + i) = ob;
  } else if (blk < 4176) {
    // ---- transpose Wk (fp32) -> WkT bf16 [c][hd] ----
    int q = blk - 4032;
    int rt = q / 12, ct = q % 12;
    auto ts = (unsigned short(*)[72])smem;
    const float* src = wqkv + (size_t)Cc * Cc;
    #pragma unroll
    for (int l = 0; l < 4; l++) {
      int idx = t + l * 256;
      int r = idx >> 4, c4 = idx & 15;
      float4 v = *(const float4*)(src + (size_t)(rt * 64 + r) * Cc + ct * 64 + c4 * 4);
      ts[r][c4 * 4 + 0] = f2bf(v.x); ts[r][c4 * 4 + 1] = f2bf(v.y);
      ts[r][c4 * 4 + 2] = f2bf(v.z); ts[r][c4 * 4 + 3] = f2bf(v.w);
    }
    __syncthreads();
    #pragma unroll
    for (int l = 0; l < 2; l++) {
      int idx = t + l * 256;
      int r2 = idx >> 3, j8 = idx & 7;
      unsigned short tmp[8];
      #pragma unroll
      for (int i = 0; i < 8; i++) tmp[i] = ts[j8 * 8 + i][r2];
      *(uint4*)(wkTb + (size_t)(ct * 64 + r2) * Cc + rt * 64 + j8 * 8) = *(uint4*)tmp;
    }
  } else {
    // ---- q rows 0,1 (fp64) ----
    int q = blk - 4176;
    int row = q & 31;
    int ot = q >> 5;
    int b = row >> 1, i = row & 1;
    float* xl = (float*)smem;
    const float* xr = x + ((size_t)b * Nn + i) * Cc;
    for (int c = t; c < Cc; c += 256) xl[c] = xr[c];
    __syncthreads();
    int w = t >> 6, lane = t & 63;
    int o = ot * 4 + w;
    const float* wr = wqkv + (size_t)o * Cc + lane * 12;
    const float* xs = xl + lane * 12;
    double acc = 0;
    #pragma unroll
    for (int k = 0; k < 12; k++) acc += (double)wr[k] * (double)xs[k];
    for (int off = 32; off > 0; off >>= 1) acc += __shfl_down(acc, off, 64);
    if (lane == 0) q01d[(size_t)row * Cc + o] = acc;
  }
}

// ---------------- K3: u rows 0,1 (fp64), c-split ----------------
__global__ __launch_bounds__(256) void k_u01(
    const float* __restrict__ wqkv, const double* __restrict__ q01d,
    double* __restrict__ u01d) {
  int blk = blockIdx.x;
  int h = blk % Hh; int i = (blk / Hh) & 1; int b = blk / (2 * Hh);
  __shared__ double qh[HD];
  const double* q = q01d + ((size_t)b * 2 + i) * Cc + h * HD;
  if (threadIdx.x < HD) qh[threadIdx.x] = q[threadIdx.x];
  __syncthreads();
  const float* wk = wqkv + (size_t)Cc * Cc;
  int c = blockIdx.y * 256 + threadIdx.x;
  double a0 = 0, a1 = 0, a2 = 0, a3 = 0;
  #pragma unroll 4
  for (int d = 0; d < HD; d += 4) {
    a0 += qh[d]     * (double)wk[(size_t)(h * HD + d) * Cc + c];
    a1 += qh[d + 1] * (double)wk[(size_t)(h * HD + d + 1) * Cc + c];
    a2 += qh[d + 2] * (double)wk[(size_t)(h * HD + d + 2) * Cc + c];
    a3 += qh[d + 3] * (double)wk[(size_t)(h * HD + d + 3) * Cc + c];
  }
  u01d[(((size_t)(b * 2 + i)) * Hh + h) * Cc + c] = (a0 + a1) + (a2 + a3);
}

// ---------------- K4 mega2: rlogits (512 blocks) + r01 (32 blocks) ---------
__global__ __launch_bounds__(256) void k_mega2(
    const double* __restrict__ u01d, const float* __restrict__ x,
    float* __restrict__ Ldp, double* __restrict__ Ld01) {
  int blk = blockIdx.x;
  int t = threadIdx.x;
  if (blk >= 512) {
    // ---- logits for columns j=0,1 (fp64 dots) ----
    int q = blk - 512;
    int b = q >> 1, i = q & 1;
    int w = t >> 6, lane = t & 63;
    for (int k = 0; k < 6; k++) {
      int p = w * 6 + k;
      int h = p >> 1, j = p & 1;
      const double* u = u01d + (((size_t)(b * 2 + i)) * Hh + h) * Cc;
      const float* xr = x + ((size_t)b * Nn + j) * Cc;
      double acc = 0;
      for (int c = lane; c < Cc; c += 64) acc += u[c] * (double)xr[c];
      for (int off = 32; off > 0; off >>= 1) acc += __shfl_down(acc, off, 64);
      if (lane == 0) Ld01[(((size_t)(b * 2 + i)) * Hh + h) * 2 + j] = acc * 0.125;
    }
    return;
  }
  // ---- routing logits, general tokens (fp64, JT=8) ----
  int b = blk >> 5, jt = (blk >> 4) & 1, cch = blk & 15;
  int c0 = cch * 48;
  int w = t >> 6, lane = t & 63;
  int g = w >> 1;
  int hh = (w & 1) * 6;
  __shared__ double ut[24][48];
  __shared__ __align__(16) float xtT[16][516];
  for (int idx = t; idx < 24 * 48; idx += 256) {
    int row = idx / 48, cc = idx % 48;
    int ig = row / 12, hr = row % 12;
    ut[row][cc] = u01d[(((size_t)(b * 2 + ig)) * Hh + hr) * Cc + c0 + cc];
  }
  double acc[6][8] = {};
  for (int s = 0; s < 3; s++) {
    #pragma unroll
    for (int l = 0; l < 8; l++) {
      int idx = t + l * 256;
      int row = idx >> 2, c4 = idx & 3;
      const float* xr = x + ((size_t)b * Nn + 2 + jt * 512 + row) * Cc + c0 + s * 16 + c4 * 4;
      float4 v = *(const float4*)xr;
      xtT[c4 * 4 + 0][row] = v.x;
      xtT[c4 * 4 + 1][row] = v.y;
      xtT[c4 * 4 + 2][row] = v.z;
      xtT[c4 * 4 + 3][row] = v.w;
    }
    __syncthreads();
    for (int cc = 0; cc < 16; cc++) {
      float4 xa = *(const float4*)&xtT[cc][lane * 8];
      float4 xb = *(const float4*)&xtT[cc][lane * 8 + 4];
      double x0 = (double)xa.x, x1 = (double)xa.y, x2 = (double)xa.z, x3 = (double)xa.w;
      double x4 = (double)xb.x, x5 = (double)xb.y, x6 = (double)xb.z, x7 = (double)xb.w;
      #pragma unroll
      for (int r = 0; r < 6; r++) {
        double uv = ut[g * 12 + hh + r][s * 16 + cc];
        acc[r][0] += uv * x0; acc[r][1] += uv * x1;
        acc[r][2] += uv * x2; acc[r][3] += uv * x3;
        acc[r][4] += uv * x4; acc[r][5] += uv * x5;
        acc[r][6] += uv * x6; acc[r][7] += uv * x7;
      }
    }
    __syncthreads();
  }
  for (int r = 0; r < 6; r++) {
    int rowo = g * 12 + hh + r;
    float4 o0, o1;
    o0.x = (float)(acc[r][0] * 0.125); o0.y = (float)(acc[r][1] * 0.125);
    o0.z = (float)(acc[r][2] * 0.125); o0.w = (float)(acc[r][3] * 0.125);
    o1.x = (float)(acc[r][4] * 0.125); o1.y = (float)(acc[r][5] * 0.125);
    o1.z = (float)(acc[r][6] * 0.125); o1.w = (float)(acc[r][7] * 0.125);
    size_t base = (((size_t)cch * Bn + b) * 24 + rowo) * 1024 + jt * 512 + lane * 8;
    *(float4*)&Ldp[base] = o0;
    *(float4*)&Ldp[base + 4] = o1;
  }
}

// ---------------- K5: sum partials + mask + softmax (fp64) ----------------
__global__ __launch_bounds__(256) void k_rsoftmax(
    const float* __restrict__ Ldp, const double* __restrict__ Ld01,
    double* __restrict__ Ld, unsigned short* __restrict__ Pb) {
  int blk = blockIdx.x;
  int h = blk % Hh; int i = (blk / Hh) & 1; int b = blk / (2 * Hh);
  double* row = Ld + (size_t)blk * Nn;
  unsigned short* prow = Pb + ((size_t)b * 216 + i * Hh + h) * NPK;
  int t = threadIdx.x;
  size_t poff = ((size_t)b * 24 + i * 12 + h) * 1024;
  constexpr size_t PSTRIDE = (size_t)Bn * 24 * 1024;
  double lv[5];
  int cnt = 0;
  double mx = -1e300;
  for (int j = t; j < Nn; j += 256) {
    double L;
    if (j < 2) {
      L = Ld01[(((size_t)(b * 2 + i)) * Hh + h) * 2 + j];
      if (i == 0 && j == 1) L = 0.0;
      if (i == 1 && j == 0) L = 0.0;
    } else {
      L = 0;
      #pragma unroll
      for (int p = 0; p < NCH; p++) L += (double)Ldp[(size_t)p * PSTRIDE + poff + (j - 2)];
    }
    lv[cnt++] = L;
    mx = fmax(mx, L);
  }
  __shared__ double sd[256];
  sd[t] = mx; __syncthreads();
  for (int st = 128; st > 0; st >>= 1) { if (t < st) sd[t] = fmax(sd[t], sd[t + st]); __syncthreads(); }
  mx = sd[0]; __syncthreads();
  double sum = 0;
  for (int k = 0; k < cnt; k++) { lv[k] = exp(lv[k] - mx); sum += lv[k]; }
  sd[t] = sum; __syncthreads();
  for (int st = 128; st > 0; st >>= 1) { if (t < st) sd[t] += sd[t + st]; __syncthreads(); }
  double inv = 1.0 / sd[0];
  int k = 0;
  for (int j = t; j < Nn; j += 256) {
    double p = lv[k++] * inv;
    row[j] = p;
    prow[j] = f2bf((float)p);
  }
  for (int j = Nn + t; j < NPK; j += 256) prow[j] = 0;
}

// ---------------- K6: fused head-means + routing ----------------
__global__ __launch_bounds__(256) void k_rsroute(
    const double* __restrict__ Ld, int* __restrict__ rowcat) {
  int b = blockIdx.x, t = threadIdx.x;
  __shared__ double vals[NG];
  __shared__ unsigned char flags[NG];
  __shared__ double redv[4];
  __shared__ int redi[4];
  __shared__ int blist[16], clist[16];
  __shared__ double blv[16], clv[16];
  for (int jg = t; jg < NG; jg += 256) {
    int j = jg + 2;
    double cs = 0, bs = 0;
    for (int h = 0; h < Hh; h++) {
      cs += Ld[(((size_t)(b * 2 + 0)) * Hh + h) * Nn + j];
      bs += Ld[(((size_t)(b * 2 + 1)) * Hh + h) * Nn + j];
    }
    cs /= 12.0; bs /= 12.0;
    vals[jg] = cs + bs;
    flags[jg] = (bs - cs) > 0.0 ? 1 : 0;
  }
  __syncthreads();
  int half = t >> 7;
  int lt = t & 127;
  int wv = t >> 6;
  int lane = t & 63;
  for (int s = 0; s < 16; s++) {
    double bv = -1e300; int bi = 0x7fffffff;
    #pragma unroll
    for (int k = 0; k < 8; k++) {
      int j = lt * 8 + k;
      double v = vals[j];
      if (flags[j] == half && v > bv) { bv = v; bi = j; }
    }
    for (int off = 32; off > 0; off >>= 1) {
      double ov = __shfl_down(bv, off, 64);
      int oi = __shfl_down(bi, off, 64);
      if (ov > bv || (ov == bv && oi < bi)) { bv = ov; bi = oi; }
    }
    if (lane == 0) { redv[wv] = bv; redi[wv] = bi; }
    __syncthreads();
    if (lt == 0) {
      double v0 = redv[half * 2], v1 = redv[half * 2 + 1];
      int i0 = redi[half * 2], i1 = redi[half * 2 + 1];
      if (v1 > v0 || (v1 == v0 && i1 < i0)) { v0 = v1; i0 = i1; }
      int win = (v0 > -1e299) ? i0 : -1;
      if (half) { blist[s] = win; blv[s] = v0; }
      else      { clist[s] = win; clv[s] = v0; }
      if (win >= 0) vals[win] = -1e300;
    }
    __syncthreads();
  }
  if (t < 16) {
    int s = t;
    int bc = blist[s];
    int cl = clist[15 - s];
    double bvv = blv[s], cvv = clv[15 - s];
    int win;
    if (bc < 0 && cl < 0) win = -1;
    else if (bc < 0) win = cl;
    else if (cl < 0) win = bc;
    else {
      bool boxwins = (bvv < cvv) || (bvv == cvv && bc > cl);
      win = boxwins ? bc : cl;
    }
    int tok = (win >= 0) ? win : 0;
    rowcat[b * NR + 2 + s] = tok + 2;
  }
  if (t == 0) { rowcat[b * NR + 0] = 0; rowcat[b * NR + 1] = 1; }
}

// ---------------- K8: q for 16 gathered rows via MFMA ----------------
__global__ __launch_bounds__(256) void k_qg_mfma(
    const unsigned short* __restrict__ xbf, const unsigned short* __restrict__ wqb,
    const int* __restrict__ rowcat, unsigned short* __restrict__ qb) {
  int mt = blockIdx.x, ng = blockIdx.y;
  int wid = threadIdx.x >> 6, lane = threadIdx.x & 63;
  int nt = ng * 4 + wid;
  int m = lane & 15, kg = lane >> 4;
  int rowi = mt * 16 + m;
  int b = rowi >> 4, s = rowi & 15;
  int tok = rowcat[b * NR + 2 + s];
  const unsigned short* abase = xbf + ((size_t)b * NPK + tok) * Cc + kg * 8;
  const unsigned short* bbase = wqb + (size_t)(nt * 16 + m) * Cc + kg * 8;
  f32x4 acc = {0, 0, 0, 0};
  for (int k0 = 0; k0 < Cc; k0 += 32) {
    short8 a = *(const short8*)(abase + k0);
    short8 bf = *(const short8*)(bbase + k0);
    acc = __builtin_amdgcn_mfma_f32_16x16x32_bf16(a, bf, acc, 0, 0, 0);
  }
  int c = nt * 16 + m;
  #pragma unroll
  for (int r = 0; r < 4; r++) {
    int rowo = mt * 16 + kg * 4 + r;
    qb[(size_t)rowo * Cc + c] = f2bf(acc[r]);
  }
}

// ---------------- K9: u for gathered rows via MFMA ----------------
__global__ __launch_bounds__(256) void k_ug_mfma(
    const unsigned short* __restrict__ qb, const unsigned short* __restrict__ wkTb,
    unsigned short* __restrict__ u16b) {
  int h = blockIdx.x, mt = blockIdx.y, ngz = blockIdx.z;
  int wid = threadIdx.x >> 6, lane = threadIdx.x & 63;
  int m = lane & 15, kg = lane >> 4;
  int rowi = mt * 16 + m;
  const unsigned short* abase = qb + (size_t)rowi * Cc + h * HD + kg * 8;
  f32x4 acc[4] = {{0,0,0,0},{0,0,0,0},{0,0,0,0},{0,0,0,0}};
  #pragma unroll
  for (int k0 = 0; k0 < HD; k0 += 32) {
    short8 a = *(const short8*)(abase + k0);
    #pragma unroll
    for (int t = 0; t < 4; t++) {
      int c = ngz * 256 + (wid * 4 + t) * 16 + m;
      short8 bf = *(const short8*)(wkTb + (size_t)c * Cc + h * HD + kg * 8 + k0);
      acc[t] = __builtin_amdgcn_mfma_f32_16x16x32_bf16(a, bf, acc[t], 0, 0, 0);
    }
  }
  #pragma unroll
  for (int t = 0; t < 4; t++) {
    int c = ngz * 256 + (wid * 4 + t) * 16 + m;
    #pragma unroll
    for (int r = 0; r < 4; r++) {
      int row = mt * 16 + kg * 4 + r;
      int b = row >> 4, s = row & 15;
      u16b[((size_t)b * 192 + s * Hh + h) * Cc + c] = f2bf(acc[t][r]);
    }
  }
}

// ---------------- K10: gathered logits — 2-wave blocks, 4m x 4n per wave ----
__global__ __launch_bounds__(128) void k_glogits_mfma(
    const unsigned short* __restrict__ u16b, const unsigned short* __restrict__ xbf,
    float* __restrict__ S) {
  int b = blockIdx.x, mg = blockIdx.y, nz = blockIdx.z;
  __shared__ __align__(16) unsigned short Bs[2][128 * 32];
  int t = threadIdx.x, w = t >> 6, lane = t & 63;
  int m = lane & 15, kg = lane >> 4;
  const unsigned short* ap[4];
  #pragma unroll
  for (int mt = 0; mt < 4; mt++)
    ap[mt] = u16b + ((size_t)b * 192 + mg * 64 + mt * 16 + m) * Cc + kg * 8;
  const unsigned short* gB[4];
  int lofs[4];
  #pragma unroll
  for (int l = 0; l < 4; l++) {
    int chunk = l * 128 + t;
    int col = chunk >> 2, kq = chunk & 3;
    gB[l] = xbf + ((size_t)b * NPK + nz * 128 + col) * Cc + kq * 8;
    lofs[l] = col * 32 + kq * 8;
  }
  constexpr int NIT = Cc / 32;  // 24
  #pragma unroll
  for (int l = 0; l < 4; l++) *(short8*)&Bs[0][lofs[l]] = *(const short8*)gB[l];
  __syncthreads();
  f32x4 acc[4][4] = {};
  for (int it = 0; it < NIT; it++) {
    int k0 = it * 32;
    int cur = it & 1;
    short8 nx[4];
    if (it + 1 < NIT) {
      #pragma unroll
      for (int l = 0; l < 4; l++) nx[l] = *(const short8*)(gB[l] + k0 + 32);
    }
    short8 a[4];
    #pragma unroll
    for (int mt = 0; mt < 4; mt++) a[mt] = *(const short8*)(ap[mt] + k0);
    #pragma unroll
    for (int tt = 0; tt < 4; tt++) {
      int col = w * 64 + tt * 16 + m;
      short8 bf = *(const short8*)&Bs[cur][col * 32 + kg * 8];
      #pragma unroll
      for (int mt = 0; mt < 4; mt++)
        acc[mt][tt] = __builtin_amdgcn_mfma_f32_16x16x32_bf16(a[mt], bf, acc[mt][tt], 0, 0, 0);
    }
    if (it + 1 < NIT) {
      #pragma unroll
      for (int l = 0; l < 4; l++) *(short8*)&Bs[cur ^ 1][lofs[l]] = nx[l];
    }
    __syncthreads();
  }
  #pragma unroll
  for (int mt = 0; mt < 4; mt++) {
    #pragma unroll
    for (int tt = 0; tt < 4; tt++) {
      int col = nz * 128 + w * 64 + tt * 16 + m;
      #pragma unroll
      for (int r = 0; r < 4; r++) {
        int row = mg * 64 + mt * 16 + kg * 4 + r;
        S[((size_t)b * 192 + row) * NPK + col] = acc[mt][tt][r] * 0.125f;
      }
    }
  }
}

// ---------------- K11: softmax for gathered rows (reads S, writes bf16 P) --
__global__ __launch_bounds__(256) void k_gsoftmax(
    const float* __restrict__ S, unsigned short* __restrict__ Pb) {
  int blk = blockIdx.x;
  int b = blk / 192, r = blk % 192;
  const float* row = S + ((size_t)b * 192 + r) * NPK;
  unsigned short* prow = Pb + ((size_t)b * 216 + 24 + r) * NPK;
  int t = threadIdx.x;
  __shared__ float sd[256];
  float mx = -1e30f;
  for (int j = t; j < Nn; j += 256) mx = fmaxf(mx, row[j]);
  sd[t] = mx; __syncthreads();
  for (int st = 128; st > 0; st >>= 1) { if (t < st) sd[t] = fmaxf(sd[t], sd[t + st]); __syncthreads(); }
  mx = sd[0]; __syncthreads();
  float sum = 0;
  for (int j = t; j < Nn; j += 256) sum += __expf(row[j] - mx);
  sd[t] = sum; __syncthreads();
  for (int st = 128; st > 0; st >>= 1) { if (t < st) sd[t] += sd[t + st]; __syncthreads(); }
  float inv = 1.0f / sd[0];
  for (int j = t; j < NPK; j += 256) {
    prow[j] = (j < Nn) ? f2bf(__expf(row[j] - mx) * inv) : (unsigned short)0;
  }
}

// ---------------- K12: wsum — 2-wave blocks, 4m x 4n per wave ----------------
__global__ __launch_bounds__(128) void k_wsum_mfma(
    const unsigned short* __restrict__ Pb, const unsigned short* __restrict__ xT,
    unsigned short* __restrict__ wsumb) {
  int b = blockIdx.x, mg = blockIdx.y, nz = blockIdx.z;
  __shared__ __align__(16) unsigned short Bs[2][128 * 32];
  int t = threadIdx.x, w = t >> 6, lane = t & 63;
  int m = lane & 15, kg = lane >> 4;
  const unsigned short* ap[4];
  #pragma unroll
  for (int mt = 0; mt < 4; mt++) {
    int r = mg * 64 + mt * 16 + m;
    int rc = r < 216 ? r : 215;
    ap[mt] = Pb + ((size_t)b * 216 + rc) * NPK + kg * 8;
  }
  const unsigned short* gB[4];
  int lofs[4];
  #pragma unroll
  for (int l = 0; l < 4; l++) {
    int chunk = l * 128 + t;
    int col = chunk >> 2, kq = chunk & 3;
    gB[l] = xT + ((size_t)b * Cc + nz * 128 + col) * NPK + kq * 8;
    lofs[l] = col * 32 + kq * 8;
  }
  constexpr int NIT = NPK / 32;  // 36
  #pragma unroll
  for (int l = 0; l < 4; l++) *(short8*)&Bs[0][lofs[l]] = *(const short8*)gB[l];
  __syncthreads();
  f32x4 acc[4][4] = {};
  for (int it = 0; it < NIT; it++) {
    int k0 = it * 32;
    int cur = it & 1;
    short8 nx[4];
    if (it + 1 < NIT) {
      #pragma unroll
      for (int l = 0; l < 4; l++) nx[l] = *(const short8*)(gB[l] + k0 + 32);
    }
    short8 a[4];
    #pragma unroll
    for (int mt = 0; mt < 4; mt++) a[mt] = *(const short8*)(ap[mt] + k0);
    #pragma unroll
    for (int tt = 0; tt < 4; tt++) {
      int col = w * 64 + tt * 16 + m;
      short8 bf = *(const short8*)&Bs[cur][col * 32 + kg * 8];
      #pragma unroll
      for (int mt = 0; mt < 4; mt++)
        acc[mt][tt] = __builtin_amdgcn_mfma_f32_16x16x32_bf16(a[mt], bf, acc[mt][tt], 0, 0, 0);
    }
    if (it + 1 < NIT) {
      #pragma unroll
      for (int l = 0; l < 4; l++) *(short8*)&Bs[cur ^ 1][lofs[l]] = nx[l];
    }
    __syncthreads();
  }
  #pragma unroll
  for (int mt = 0; mt < 4; mt++) {
    #pragma unroll
    for (int tt = 0; tt < 4; tt++) {
      int col = nz * 128 + w * 64 + tt * 16 + m;
      #pragma unroll
      for (int r = 0; r < 4; r++) {
        int row = mg * 64 + mt * 16 + kg * 4 + r;
        if (row < 216) wsumb[((size_t)b * 216 + row) * Cc + col] = f2bf(acc[mt][tt][r]);
      }
    }
  }
}

// ---------------- K13: attnout = Wv * wsum via MFMA ----------------
__global__ __launch_bounds__(256) void k_attnout_mfma(
    const unsigned short* __restrict__ wsumb, const unsigned short* __restrict__ wvb,
    unsigned short* __restrict__ aob) {
  int h = blockIdx.x, mt = blockIdx.y;
  int wid = threadIdx.x >> 6, lane = threadIdx.x & 63;
  int m = lane & 15, kg = lane >> 4;
  int row = mt * 16 + m;
  int b = row / NR, i = row % NR;
  const unsigned short* abase = wsumb + ((size_t)b * 216 + i * 12 + h) * Cc + kg * 8;
  const unsigned short* bbase = wvb + (size_t)(h * HD + wid * 16 + m) * Cc + kg * 8;
  f32x4 acc = {0, 0, 0, 0};
  for (int k0 = 0; k0 < Cc; k0 += 32) {
    short8 a = *(const short8*)(abase + k0);
    short8 bf = *(const short8*)(bbase + k0);
    acc = __builtin_amdgcn_mfma_f32_16x16x32_bf16(a, bf, acc, 0, 0, 0);
  }
  #pragma unroll
  for (int r = 0; r < 4; r++) {
    int orow = mt * 16 + kg * 4 + r;
    int ocol = h * HD + wid * 16 + m;
    aob[(size_t)orow * Cc + ocol] = f2bf(acc[r]);
  }
}

// ---------------- K14: proj via MFMA + bias + residual + scatter ----------
__global__ __launch_bounds__(256) void k_proj_mfma(
    const unsigned short* __restrict__ aob, const unsigned short* __restrict__ wpb,
    const float* __restrict__ bproj, const int* __restrict__ rowcat,
    const float* __restrict__ gen, const float* __restrict__ cls,
    const float* __restrict__ box, float* __restrict__ out) {
  int mt = blockIdx.x, ng = blockIdx.y;
  int wid = threadIdx.x >> 6, lane = threadIdx.x & 63;
  int nt = ng * 4 + wid;
  int m = lane & 15, kg = lane >> 4;
  const unsigned short* abase = aob + (size_t)(mt * 16 + m) * Cc + kg * 8;
  const unsigned short* bbase = wpb + (size_t)(nt * 16 + m) * Cc + kg * 8;
  f32x4 acc = {0, 0, 0, 0};
  for (int k0 = 0; k0 < Cc; k0 += 32) {
    short8 a = *(const short8*)(abase + k0);
    short8 bf = *(const short8*)(bbase + k0);
    acc = __builtin_amdgcn_mfma_f32_16x16x32_bf16(a, bf, acc, 0, 0, 0);
  }
  int c = nt * 16 + m;
  float bp = bproj[c];
  #pragma unroll
  for (int r = 0; r < 4; r++) {
    int bi = mt * 16 + kg * 4 + r;
    int b = bi / NR, i = bi % NR;
    int tok = rowcat[b * NR + i];
    const float* src = (tok == 0) ? cls + (size_t)b * Cc
                     : (tok == 1) ? box + (size_t)b * Cc
                                  : gen + ((size_t)b * NG + tok - 2) * Cc;
    float val = acc[r] + bp + src[c];
    float* dst;
    if (i == 0)       dst = out + ((size_t)b * 9 + 0) * Cc;
    else if (i == 1)  dst = out + (size_t)Bn * 9 * Cc + ((size_t)b * 9 + 0) * Cc;
    else if (i < 10)  dst = out + ((size_t)b * 9 + (i - 1)) * Cc;
    else              dst = out + (size_t)Bn * 9 * Cc + ((size_t)b * 9 + (i - 9)) * Cc;
    dst[c] = val;
  }
}

}  // namespace

extern "C" void kernel_launch(void* const* d_in, const int* in_sizes, int n_in,
                              void* d_out, int out_size, void* d_ws, size_t ws_size,
                              hipStream_t stream) {
  (void)in_sizes; (void)n_in; (void)out_size; (void)ws_size;
  const float* gen   = (const float*)d_in[0];
  const float* cls   = (const float*)d_in[1];
  const float* box   = (const float*)d_in[2];
  const float* wqkv  = (const float*)d_in[3];
  const float* wproj = (const float*)d_in[4];
  const float* bproj = (const float*)d_in[5];
  const float* gamma = (const float*)d_in[6];
  const float* beta  = (const float*)d_in[7];
  float* out = (float*)d_out;

  char* ws = (char*)d_ws;
  size_t off = 0;
  auto alloc = [&](size_t bytes) { void* p = ws + off; off += (bytes + 255) & ~(size_t)255; return p; };
  float* x             = (float*)alloc((size_t)Bn * Nn * Cc * 4);
  unsigned short* xbf  = (unsigned short*)alloc((size_t)Bn * NPK * Cc * 2);
  unsigned short* xT   = (unsigned short*)alloc((size_t)Bn * Cc * NPK * 2);
  unsigned short* qb   = (unsigned short*)alloc((size_t)256 * Cc * 2);
  unsigned short* u16b = (unsigned short*)alloc((size_t)Bn * 192 * Cc * 2);
  float* S             = (float*)alloc((size_t)Bn * 192 * NPK * 4);
  unsigned short* Pb   = (unsigned short*)alloc((size_t)Bn * 216 * NPK * 2);
  unsigned short* wsumb= (unsigned short*)alloc((size_t)Bn * 216 * Cc * 2);
  unsigned short* aob  = (unsigned short*)alloc((size_t)288 * Cc * 2);
  unsigned short* wqb  = (unsigned short*)alloc((size_t)Cc * Cc * 2);
  unsigned short* wvb  = (unsigned short*)alloc((size_t)Cc * Cc * 2);
  unsigned short* wpb  = (unsigned short*)alloc((size_t)Cc * Cc * 2);
  unsigned short* wkTb = (unsigned short*)alloc((size_t)Cc * Cc * 2);
  double* q01d         = (double*)alloc((size_t)Bn * 2 * Cc * 8);
  double* u01d         = (double*)alloc((size_t)Bn * 2 * Hh * Cc * 8);
  double* Ld           = (double*)alloc((size_t)Bn * 2 * Hh * Nn * 8);
  double* Ld01         = (double*)alloc((size_t)Bn * 2 * Hh * 2 * 8);
  float* Ldp           = (float*)alloc((size_t)NCH * Bn * 24 * 1024 * 4);
  int* rowcat          = (int*)alloc((size_t)Bn * NR * 4);

  k_ln<<<Bn * Nn + 96, 256, 0, stream>>>(gen, cls, box, gamma, beta, x, xbf);
  k_mega1<<<10320, 256, 0, stream>>>(xbf, xT, wqkv, wproj, wqb, wvb, wpb, wkTb, x, q01d);
  k_u01<<<dim3(Bn * 2 * Hh, 3), 256, 0, stream>>>(wqkv, q01d, u01d);
  k_mega2<<<544, 256, 0, stream>>>(u01d, x, Ldp, Ld01);
  k_rsoftmax<<<Bn * 2 * Hh, 256, 0, stream>>>(Ldp, Ld01, Ld, Pb);
  k_rsroute<<<Bn, 256, 0, stream>>>(Ld, rowcat);
  k_qg_mfma<<<dim3(16, 12), 256, 0, stream>>>(xbf, wqb, rowcat, qb);
  k_ug_mfma<<<dim3(Hh, 16, 3), 256, 0, stream>>>(qb, wkTb, u16b);
  k_glogits_mfma<<<dim3(Bn, 3, 9), 128, 0, stream>>>(u16b, xbf, S);
  k_gsoftmax<<<Bn * 192, 256, 0, stream>>>(S, Pb);
  k_wsum_mfma<<<dim3(Bn, 4, 6), 128, 0, stream>>>(Pb, xT, wsumb);
  k_attnout_mfma<<<dim3(Hh, 18), 256, 0, stream>>>(wsumb, wvb, aob);
  k_proj_mfma<<<dim3(18, 12), 256, 0, stream>>>(aob, wpb, bproj, rowcat, gen, cls, box, out);
}

// Round 12
// 294.135 us; speedup vs baseline: 1.0671x; 1.0155x over previous
//
#include <hip/hip_runtime.h>
#include <math.h>

namespace {

constexpr int Bn = 16;    // batch
constexpr int NG = 1024;  // general tokens
constexpr int Cc = 768;   // channels
constexpr int Hh = 12;    // heads
constexpr int HD = 64;    // head dim
constexpr int Nn = 1026;  // total tokens (cls, box, general)
constexpr int NR = 18;    // rows we actually need: 0,1 + 16 routed
constexpr int NPK = 1152; // padded token count (9*128) for MFMA K / N tiles
constexpr int NCH = 16;   // c-chunks for k_rlogits (c-chunk = 48)

typedef __attribute__((ext_vector_type(8))) short short8;
typedef __attribute__((ext_vector_type(4))) float f32x4;

__device__ inline unsigned short f2bf(float f) {
  unsigned u = __float_as_uint(f);
  unsigned r = u + 0x7FFFu + ((u >> 16) & 1u);
  return (unsigned short)(r >> 16);
}

// ---------------- K1: LayerNorm (fp64 accumulation) + xbf pad-zero ---------
__global__ __launch_bounds__(256) void k_ln(
    const float* __restrict__ gen, const float* __restrict__ cls,
    const float* __restrict__ box, const float* __restrict__ gamma,
    const float* __restrict__ beta, float* __restrict__ x,
    unsigned short* __restrict__ xbf) {
  int blk = blockIdx.x;
  int t = threadIdx.x;
  if (blk >= Bn * Nn) {
    constexpr int PERB = (NPK - Nn) * Cc / 2;  // uints per batch
    int idx = (blk - Bn * Nn) * 256 + t;
    int total = Bn * PERB;
    for (int i = idx; i < total; i += 96 * 256) {
      int b = i / PERB, r = i % PERB;
      unsigned int* p = (unsigned int*)(xbf + ((size_t)b * NPK + Nn) * Cc);
      p[r] = 0u;
    }
    return;
  }
  int b = blk / Nn, n = blk % Nn;
  const float* src = (n == 0) ? cls + (size_t)b * Cc
                   : (n == 1) ? box + (size_t)b * Cc
                              : gen + ((size_t)b * NG + (n - 2)) * Cc;
  float v0 = src[t], v1 = src[t + 256], v2 = src[t + 512];
  __shared__ double red[8];
  double s = (double)v0 + (double)v1 + (double)v2;
  for (int o = 32; o > 0; o >>= 1) s += __shfl_down(s, o, 64);
  int wid = t >> 6, lid = t & 63;
  if (lid == 0) red[wid] = s;
  __syncthreads();
  if (t == 0) red[4] = (red[0] + red[1] + red[2] + red[3]) / Cc;
  __syncthreads();
  double mean = red[4];
  double d0 = (double)v0 - mean, d1 = (double)v1 - mean, d2 = (double)v2 - mean;
  double sq = d0 * d0 + d1 * d1 + d2 * d2;
  for (int o = 32; o > 0; o >>= 1) sq += __shfl_down(sq, o, 64);
  __syncthreads();
  if (lid == 0) red[wid] = sq;
  __syncthreads();
  if (t == 0) {
    double var = (red[0] + red[1] + red[2] + red[3]) / Cc;
    red[5] = 1.0 / sqrt(var + 1e-5);
  }
  __syncthreads();
  double rs = red[5];
  float* dst = x + ((size_t)b * Nn + n) * Cc;
  unsigned short* dbf = xbf + ((size_t)b * NPK + n) * Cc;
  float o0 = (float)(d0 * rs * (double)gamma[t]       + (double)beta[t]);
  float o1 = (float)(d1 * rs * (double)gamma[t + 256] + (double)beta[t + 256]);
  float o2 = (float)(d2 * rs * (double)gamma[t + 512] + (double)beta[t + 512]);
  dst[t] = o0; dst[t + 256] = o1; dst[t + 512] = o2;
  dbf[t] = f2bf(o0); dbf[t + 256] = f2bf(o1); dbf[t + 512] = f2bf(o2);
}

// ---------------- K2 mega1: xt (3456) + wcvt (576) + wkt (144) + q01 (6144)
__global__ __launch_bounds__(256) void k_mega1(
    const unsigned short* __restrict__ xbf, unsigned short* __restrict__ xT,
    const float* __restrict__ wqkv, const float* __restrict__ wproj,
    unsigned short* __restrict__ wqb, unsigned short* __restrict__ wvb,
    unsigned short* __restrict__ wpb, unsigned short* __restrict__ wkTb,
    const float* __restrict__ x, double* __restrict__ q01d) {
  __shared__ __align__(16) char smem[64 * 80 * 2];
  int blk = blockIdx.x;
  int t = threadIdx.x;
  if (blk < 3456) {
    int b = blk / 216, rem = blk % 216;
    int jt = rem / 12, ct = rem % 12;
    int j0 = jt * 64, c0 = ct * 64;
    auto ts = (unsigned short(*)[80])smem;
    #pragma unroll
    for (int l = 0; l < 2; l++) {
      int chunk = t + l * 256;
      int r = chunk >> 3, c8 = chunk & 7;
      uint4 v = *(const uint4*)(xbf + ((size_t)b * NPK + j0 + r) * Cc + c0 + c8 * 8);
      *(uint4*)&ts[r][c8 * 8] = v;
    }
    __syncthreads();
    #pragma unroll
    for (int l = 0; l < 2; l++) {
      int chunk = t + l * 256;
      int orow = chunk >> 3, j8 = chunk & 7;
      unsigned short tmp[8];
      #pragma unroll
      for (int i = 0; i < 8; i++) tmp[i] = ts[j8 * 8 + i][orow];
      *(uint4*)(xT + ((size_t)b * Cc + c0 + orow) * NPK + j0 + j8 * 8) = *(uint4*)tmp;
    }
  } else if (blk < 4032) {
    int i = ((blk - 3456) * 256 + t) * 4;
    const float* wq = wqkv;
    const float* wv = wqkv + (size_t)2 * Cc * Cc;
    float4 q = *(const float4*)(wq + i);
    float4 a = *(const float4*)(wv + i);
    float4 b = *(const float4*)(wproj + i);
    ushort4 oq, oa, ob;
    oq.x = f2bf(q.x); oq.y = f2bf(q.y); oq.z = f2bf(q.z); oq.w = f2bf(q.w);
    oa.x = f2bf(a.x); oa.y = f2bf(a.y); oa.z = f2bf(a.z); oa.w = f2bf(a.w);
    ob.x = f2bf(b.x); ob.y = f2bf(b.y); ob.z = f2bf(b.z); ob.w = f2bf(b.w);
    *(ushort4*)(wqb + i) = oq;
    *(ushort4*)(wvb + i) = oa;
    *(ushort4*)(wpb + i) = ob;
  } else if (blk < 4176) {
    int q = blk - 4032;
    int rt = q / 12, ct = q % 12;
    auto ts = (unsigned short(*)[72])smem;
    const float* src = wqkv + (size_t)Cc * Cc;
    #pragma unroll
    for (int l = 0; l < 4; l++) {
      int idx = t + l * 256;
      int r = idx >> 4, c4 = idx & 15;
      float4 v = *(const float4*)(src + (size_t)(rt * 64 + r) * Cc + ct * 64 + c4 * 4);
      ts[r][c4 * 4 + 0] = f2bf(v.x); ts[r][c4 * 4 + 1] = f2bf(v.y);
      ts[r][c4 * 4 + 2] = f2bf(v.z); ts[r][c4 * 4 + 3] = f2bf(v.w);
    }
    __syncthreads();
    #pragma unroll
    for (int l = 0; l < 2; l++) {
      int idx = t + l * 256;
      int r2 = idx >> 3, j8 = idx & 7;
      unsigned short tmp[8];
      #pragma unroll
      for (int i = 0; i < 8; i++) tmp[i] = ts[j8 * 8 + i][r2];
      *(uint4*)(wkTb + (size_t)(ct * 64 + r2) * Cc + rt * 64 + j8 * 8) = *(uint4*)tmp;
    }
  } else {
    int q = blk - 4176;
    int row = q & 31;
    int ot = q >> 5;
    int b = row >> 1, i = row & 1;
    float* xl = (float*)smem;
    const float* xr = x + ((size_t)b * Nn + i) * Cc;
    for (int c = t; c < Cc; c += 256) xl[c] = xr[c];
    __syncthreads();
    int w = t >> 6, lane = t & 63;
    int o = ot * 4 + w;
    const float* wr = wqkv + (size_t)o * Cc + lane * 12;
    const float* xs = xl + lane * 12;
    double acc = 0;
    #pragma unroll
    for (int k = 0; k < 12; k++) acc += (double)wr[k] * (double)xs[k];
    for (int off = 32; off > 0; off >>= 1) acc += __shfl_down(acc, off, 64);
    if (lane == 0) q01d[(size_t)row * Cc + o] = acc;
  }
}

// ---------------- K3: u rows 0,1 (fp64), c-split ----------------
__global__ __launch_bounds__(256) void k_u01(
    const float* __restrict__ wqkv, const double* __restrict__ q01d,
    double* __restrict__ u01d) {
  int blk = blockIdx.x;
  int h = blk % Hh; int i = (blk / Hh) & 1; int b = blk / (2 * Hh);
  __shared__ double qh[HD];
  const double* q = q01d + ((size_t)b * 2 + i) * Cc + h * HD;
  if (threadIdx.x < HD) qh[threadIdx.x] = q[threadIdx.x];
  __syncthreads();
  const float* wk = wqkv + (size_t)Cc * Cc;
  int c = blockIdx.y * 256 + threadIdx.x;
  double a0 = 0, a1 = 0, a2 = 0, a3 = 0;
  #pragma unroll 4
  for (int d = 0; d < HD; d += 4) {
    a0 += qh[d]     * (double)wk[(size_t)(h * HD + d) * Cc + c];
    a1 += qh[d + 1] * (double)wk[(size_t)(h * HD + d + 1) * Cc + c];
    a2 += qh[d + 2] * (double)wk[(size_t)(h * HD + d + 2) * Cc + c];
    a3 += qh[d + 3] * (double)wk[(size_t)(h * HD + d + 3) * Cc + c];
  }
  u01d[(((size_t)(b * 2 + i)) * Hh + h) * Cc + c] = (a0 + a1) + (a2 + a3);
}

// ---------------- K4 mega2: rlogits (1024 blocks, JT=4) + r01 (32 blocks) --
// rlogits: b = blk>>6, jt = (blk>>4)&3 (256 j), cch = blk&15 (48 c).
// Wave w: g=w>>1, h in [(w&1)*6,+6). Lane owns 4 j. acc[6][4] fp64 (~48 VGPR)
// -> high occupancy; xtT reads 16B/lane spaced = conflict-free.
__global__ __launch_bounds__(256) void k_mega2(
    const double* __restrict__ u01d, const float* __restrict__ x,
    float* __restrict__ Ldp, double* __restrict__ Ld01) {
  int blk = blockIdx.x;
  int t = threadIdx.x;
  if (blk >= 1024) {
    // ---- logits for columns j=0,1 (fp64 dots) ----
    int q = blk - 1024;
    int b = q >> 1, i = q & 1;
    int w = t >> 6, lane = t & 63;
    for (int k = 0; k < 6; k++) {
      int p = w * 6 + k;
      int h = p >> 1, j = p & 1;
      const double* u = u01d + (((size_t)(b * 2 + i)) * Hh + h) * Cc;
      const float* xr = x + ((size_t)b * Nn + j) * Cc;
      double acc = 0;
      for (int c = lane; c < Cc; c += 64) acc += u[c] * (double)xr[c];
      for (int off = 32; off > 0; off >>= 1) acc += __shfl_down(acc, off, 64);
      if (lane == 0) Ld01[(((size_t)(b * 2 + i)) * Hh + h) * 2 + j] = acc * 0.125;
    }
    return;
  }
  // ---- routing logits, general tokens (fp64, JT=4) ----
  int b = blk >> 6, jt = (blk >> 4) & 3, cch = blk & 15;
  int c0 = cch * 48;
  int w = t >> 6, lane = t & 63;
  int g = w >> 1;
  int hh = (w & 1) * 6;
  __shared__ double ut[24][48];
  __shared__ __align__(16) float xtT[16][260];
  for (int idx = t; idx < 24 * 48; idx += 256) {
    int row = idx / 48, cc = idx % 48;
    int ig = row / 12, hr = row % 12;
    ut[row][cc] = u01d[(((size_t)(b * 2 + ig)) * Hh + hr) * Cc + c0 + cc];
  }
  double acc[6][4] = {};
  for (int s = 0; s < 3; s++) {
    #pragma unroll
    for (int l = 0; l < 4; l++) {
      int idx = t + l * 256;
      int row = idx >> 2, c4 = idx & 3;
      const float* xr = x + ((size_t)b * Nn + 2 + jt * 256 + row) * Cc + c0 + s * 16 + c4 * 4;
      float4 v = *(const float4*)xr;
      xtT[c4 * 4 + 0][row] = v.x;
      xtT[c4 * 4 + 1][row] = v.y;
      xtT[c4 * 4 + 2][row] = v.z;
      xtT[c4 * 4 + 3][row] = v.w;
    }
    __syncthreads();
    for (int cc = 0; cc < 16; cc++) {
      float4 xa = *(const float4*)&xtT[cc][lane * 4];
      double x0 = (double)xa.x, x1 = (double)xa.y, x2 = (double)xa.z, x3 = (double)xa.w;
      #pragma unroll
      for (int r = 0; r < 6; r++) {
        double uv = ut[g * 12 + hh + r][s * 16 + cc];
        acc[r][0] += uv * x0; acc[r][1] += uv * x1;
        acc[r][2] += uv * x2; acc[r][3] += uv * x3;
      }
    }
    __syncthreads();
  }
  for (int r = 0; r < 6; r++) {
    int rowo = g * 12 + hh + r;
    float4 o0;
    o0.x = (float)(acc[r][0] * 0.125); o0.y = (float)(acc[r][1] * 0.125);
    o0.z = (float)(acc[r][2] * 0.125); o0.w = (float)(acc[r][3] * 0.125);
    size_t base = (((size_t)cch * Bn + b) * 24 + rowo) * 1024 + jt * 256 + lane * 4;
    *(float4*)&Ldp[base] = o0;
  }
}

// ---------------- K5: sum partials + mask + softmax (fp64) ----------------
__global__ __launch_bounds__(256) void k_rsoftmax(
    const float* __restrict__ Ldp, const double* __restrict__ Ld01,
    double* __restrict__ Ld, unsigned short* __restrict__ Pb) {
  int blk = blockIdx.x;
  int h = blk % Hh; int i = (blk / Hh) & 1; int b = blk / (2 * Hh);
  double* row = Ld + (size_t)blk * Nn;
  unsigned short* prow = Pb + ((size_t)b * 216 + i * Hh + h) * NPK;
  int t = threadIdx.x;
  size_t poff = ((size_t)b * 24 + i * 12 + h) * 1024;
  constexpr size_t PSTRIDE = (size_t)Bn * 24 * 1024;
  double lv[5];
  int cnt = 0;
  double mx = -1e300;
  for (int j = t; j < Nn; j += 256) {
    double L;
    if (j < 2) {
      L = Ld01[(((size_t)(b * 2 + i)) * Hh + h) * 2 + j];
      if (i == 0 && j == 1) L = 0.0;
      if (i == 1 && j == 0) L = 0.0;
    } else {
      L = 0;
      #pragma unroll
      for (int p = 0; p < NCH; p++) L += (double)Ldp[(size_t)p * PSTRIDE + poff + (j - 2)];
    }
    lv[cnt++] = L;
    mx = fmax(mx, L);
  }
  __shared__ double sd[256];
  sd[t] = mx; __syncthreads();
  for (int st = 128; st > 0; st >>= 1) { if (t < st) sd[t] = fmax(sd[t], sd[t + st]); __syncthreads(); }
  mx = sd[0]; __syncthreads();
  double sum = 0;
  for (int k = 0; k < cnt; k++) { lv[k] = exp(lv[k] - mx); sum += lv[k]; }
  sd[t] = sum; __syncthreads();
  for (int st = 128; st > 0; st >>= 1) { if (t < st) sd[t] += sd[t + st]; __syncthreads(); }
  double inv = 1.0 / sd[0];
  int k = 0;
  for (int j = t; j < Nn; j += 256) {
    double p = lv[k++] * inv;
    row[j] = p;
    prow[j] = f2bf((float)p);
  }
  for (int j = Nn + t; j < NPK; j += 256) prow[j] = 0;
}

// ---------------- K6: fused head-means + routing ----------------
__global__ __launch_bounds__(256) void k_rsroute(
    const double* __restrict__ Ld, int* __restrict__ rowcat) {
  int b = blockIdx.x, t = threadIdx.x;
  __shared__ double vals[NG];
  __shared__ unsigned char flags[NG];
  __shared__ double redv[4];
  __shared__ int redi[4];
  __shared__ int blist[16], clist[16];
  __shared__ double blv[16], clv[16];
  for (int jg = t; jg < NG; jg += 256) {
    int j = jg + 2;
    double cs = 0, bs = 0;
    for (int h = 0; h < Hh; h++) {
      cs += Ld[(((size_t)(b * 2 + 0)) * Hh + h) * Nn + j];
      bs += Ld[(((size_t)(b * 2 + 1)) * Hh + h) * Nn + j];
    }
    cs /= 12.0; bs /= 12.0;
    vals[jg] = cs + bs;
    flags[jg] = (bs - cs) > 0.0 ? 1 : 0;
  }
  __syncthreads();
  int half = t >> 7;
  int lt = t & 127;
  int wv = t >> 6;
  int lane = t & 63;
  for (int s = 0; s < 16; s++) {
    double bv = -1e300; int bi = 0x7fffffff;
    #pragma unroll
    for (int k = 0; k < 8; k++) {
      int j = lt * 8 + k;
      double v = vals[j];
      if (flags[j] == half && v > bv) { bv = v; bi = j; }
    }
    for (int off = 32; off > 0; off >>= 1) {
      double ov = __shfl_down(bv, off, 64);
      int oi = __shfl_down(bi, off, 64);
      if (ov > bv || (ov == bv && oi < bi)) { bv = ov; bi = oi; }
    }
    if (lane == 0) { redv[wv] = bv; redi[wv] = bi; }
    __syncthreads();
    if (lt == 0) {
      double v0 = redv[half * 2], v1 = redv[half * 2 + 1];
      int i0 = redi[half * 2], i1 = redi[half * 2 + 1];
      if (v1 > v0 || (v1 == v0 && i1 < i0)) { v0 = v1; i0 = i1; }
      int win = (v0 > -1e299) ? i0 : -1;
      if (half) { blist[s] = win; blv[s] = v0; }
      else      { clist[s] = win; clv[s] = v0; }
      if (win >= 0) vals[win] = -1e300;
    }
    __syncthreads();
  }
  if (t < 16) {
    int s = t;
    int bc = blist[s];
    int cl = clist[15 - s];
    double bvv = blv[s], cvv = clv[15 - s];
    int win;
    if (bc < 0 && cl < 0) win = -1;
    else if (bc < 0) win = cl;
    else if (cl < 0) win = bc;
    else {
      bool boxwins = (bvv < cvv) || (bvv == cvv && bc > cl);
      win = boxwins ? bc : cl;
    }
    int tok = (win >= 0) ? win : 0;
    rowcat[b * NR + 2 + s] = tok + 2;
  }
  if (t == 0) { rowcat[b * NR + 0] = 0; rowcat[b * NR + 1] = 1; }
}

// ---------------- K8: q for 16 gathered rows via MFMA ----------------
__global__ __launch_bounds__(256) void k_qg_mfma(
    const unsigned short* __restrict__ xbf, const unsigned short* __restrict__ wqb,
    const int* __restrict__ rowcat, unsigned short* __restrict__ qb) {
  int mt = blockIdx.x, ng = blockIdx.y;
  int wid = threadIdx.x >> 6, lane = threadIdx.x & 63;
  int nt = ng * 4 + wid;
  int m = lane & 15, kg = lane >> 4;
  int rowi = mt * 16 + m;
  int b = rowi >> 4, s = rowi & 15;
  int tok = rowcat[b * NR + 2 + s];
  const unsigned short* abase = xbf + ((size_t)b * NPK + tok) * Cc + kg * 8;
  const unsigned short* bbase = wqb + (size_t)(nt * 16 + m) * Cc + kg * 8;
  f32x4 acc = {0, 0, 0, 0};
  for (int k0 = 0; k0 < Cc; k0 += 32) {
    short8 a = *(const short8*)(abase + k0);
    short8 bf = *(const short8*)(bbase + k0);
    acc = __builtin_amdgcn_mfma_f32_16x16x32_bf16(a, bf, acc, 0, 0, 0);
  }
  int c = nt * 16 + m;
  #pragma unroll
  for (int r = 0; r < 4; r++) {
    int rowo = mt * 16 + kg * 4 + r;
    qb[(size_t)rowo * Cc + c] = f2bf(acc[r]);
  }
}

// ---------------- K9: u for gathered rows via MFMA ----------------
__global__ __launch_bounds__(256) void k_ug_mfma(
    const unsigned short* __restrict__ qb, const unsigned short* __restrict__ wkTb,
    unsigned short* __restrict__ u16b) {
  int h = blockIdx.x, mt = blockIdx.y, ngz = blockIdx.z;
  int wid = threadIdx.x >> 6, lane = threadIdx.x & 63;
  int m = lane & 15, kg = lane >> 4;
  int rowi = mt * 16 + m;
  const unsigned short* abase = qb + (size_t)rowi * Cc + h * HD + kg * 8;
  f32x4 acc[4] = {{0,0,0,0},{0,0,0,0},{0,0,0,0},{0,0,0,0}};
  #pragma unroll
  for (int k0 = 0; k0 < HD; k0 += 32) {
    short8 a = *(const short8*)(abase + k0);
    #pragma unroll
    for (int t = 0; t < 4; t++) {
      int c = ngz * 256 + (wid * 4 + t) * 16 + m;
      short8 bf = *(const short8*)(wkTb + (size_t)c * Cc + h * HD + kg * 8 + k0);
      acc[t] = __builtin_amdgcn_mfma_f32_16x16x32_bf16(a, bf, acc[t], 0, 0, 0);
    }
  }
  #pragma unroll
  for (int t = 0; t < 4; t++) {
    int c = ngz * 256 + (wid * 4 + t) * 16 + m;
    #pragma unroll
    for (int r = 0; r < 4; r++) {
      int row = mt * 16 + kg * 4 + r;
      int b = row >> 4, s = row & 15;
      u16b[((size_t)b * 192 + s * Hh + h) * Cc + c] = f2bf(acc[t][r]);
    }
  }
}

// ---------------- K10: gathered logits — 2-wave blocks, 4m x 4n per wave ----
__global__ __launch_bounds__(128) void k_glogits_mfma(
    const unsigned short* __restrict__ u16b, const unsigned short* __restrict__ xbf,
    float* __restrict__ S) {
  int b = blockIdx.x, mg = blockIdx.y, nz = blockIdx.z;
  __shared__ __align__(16) unsigned short Bs[2][128 * 32];
  int t = threadIdx.x, w = t >> 6, lane = t & 63;
  int m = lane & 15, kg = lane >> 4;
  const unsigned short* ap[4];
  #pragma unroll
  for (int mt = 0; mt < 4; mt++)
    ap[mt] = u16b + ((size_t)b * 192 + mg * 64 + mt * 16 + m) * Cc + kg * 8;
  const unsigned short* gB[4];
  int lofs[4];
  #pragma unroll
  for (int l = 0; l < 4; l++) {
    int chunk = l * 128 + t;
    int col = chunk >> 2, kq = chunk & 3;
    gB[l] = xbf + ((size_t)b * NPK + nz * 128 + col) * Cc + kq * 8;
    lofs[l] = col * 32 + kq * 8;
  }
  constexpr int NIT = Cc / 32;  // 24
  #pragma unroll
  for (int l = 0; l < 4; l++) *(short8*)&Bs[0][lofs[l]] = *(const short8*)gB[l];
  __syncthreads();
  f32x4 acc[4][4] = {};
  for (int it = 0; it < NIT; it++) {
    int k0 = it * 32;
    int cur = it & 1;
    short8 nx[4];
    if (it + 1 < NIT) {
      #pragma unroll
      for (int l = 0; l < 4; l++) nx[l] = *(const short8*)(gB[l] + k0 + 32);
    }
    short8 a[4];
    #pragma unroll
    for (int mt = 0; mt < 4; mt++) a[mt] = *(const short8*)(ap[mt] + k0);
    #pragma unroll
    for (int tt = 0; tt < 4; tt++) {
      int col = w * 64 + tt * 16 + m;
      short8 bf = *(const short8*)&Bs[cur][col * 32 + kg * 8];
      #pragma unroll
      for (int mt = 0; mt < 4; mt++)
        acc[mt][tt] = __builtin_amdgcn_mfma_f32_16x16x32_bf16(a[mt], bf, acc[mt][tt], 0, 0, 0);
    }
    if (it + 1 < NIT) {
      #pragma unroll
      for (int l = 0; l < 4; l++) *(short8*)&Bs[cur ^ 1][lofs[l]] = nx[l];
    }
    __syncthreads();
  }
  #pragma unroll
  for (int mt = 0; mt < 4; mt++) {
    #pragma unroll
    for (int tt = 0; tt < 4; tt++) {
      int col = nz * 128 + w * 64 + tt * 16 + m;
      #pragma unroll
      for (int r = 0; r < 4; r++) {
        int row = mg * 64 + mt * 16 + kg * 4 + r;
        S[((size_t)b * 192 + row) * NPK + col] = acc[mt][tt][r] * 0.125f;
      }
    }
  }
}

// ---------------- K11: softmax for gathered rows (reads S, writes bf16 P) --
__global__ __launch_bounds__(256) void k_gsoftmax(
    const float* __restrict__ S, unsigned short* __restrict__ Pb) {
  int blk = blockIdx.x;
  int b = blk / 192, r = blk % 192;
  const float* row = S + ((size_t)b * 192 + r) * NPK;
  unsigned short* prow = Pb + ((size_t)b * 216 + 24 + r) * NPK;
  int t = threadIdx.x;
  __shared__ float sd[256];
  float mx = -1e30f;
  for (int j = t; j < Nn; j += 256) mx = fmaxf(mx, row[j]);
  sd[t] = mx; __syncthreads();
  for (int st = 128; st > 0; st >>= 1) { if (t < st) sd[t] = fmaxf(sd[t], sd[t + st]); __syncthreads(); }
  mx = sd[0]; __syncthreads();
  float sum = 0;
  for (int j = t; j < Nn; j += 256) sum += __expf(row[j] - mx);
  sd[t] = sum; __syncthreads();
  for (int st = 128; st > 0; st >>= 1) { if (t < st) sd[t] += sd[t + st]; __syncthreads(); }
  float inv = 1.0f / sd[0];
  for (int j = t; j < NPK; j += 256) {
    prow[j] = (j < Nn) ? f2bf(__expf(row[j] - mx) * inv) : (unsigned short)0;
  }
}

// ---------------- K12: wsum — 2-wave blocks, 4m x 4n per wave ----------------
__global__ __launch_bounds__(128) void k_wsum_mfma(
    const unsigned short* __restrict__ Pb, const unsigned short* __restrict__ xT,
    unsigned short* __restrict__ wsumb) {
  int b = blockIdx.x, mg = blockIdx.y, nz = blockIdx.z;
  __shared__ __align__(16) unsigned short Bs[2][128 * 32];
  int t = threadIdx.x, w = t >> 6, lane = t & 63;
  int m = lane & 15, kg = lane >> 4;
  const unsigned short* ap[4];
  #pragma unroll
  for (int mt = 0; mt < 4; mt++) {
    int r = mg * 64 + mt * 16 + m;
    int rc = r < 216 ? r : 215;
    ap[mt] = Pb + ((size_t)b * 216 + rc) * NPK + kg * 8;
  }
  const unsigned short* gB[4];
  int lofs[4];
  #pragma unroll
  for (int l = 0; l < 4; l++) {
    int chunk = l * 128 + t;
    int col = chunk >> 2, kq = chunk & 3;
    gB[l] = xT + ((size_t)b * Cc + nz * 128 + col) * NPK + kq * 8;
    lofs[l] = col * 32 + kq * 8;
  }
  constexpr int NIT = NPK / 32;  // 36
  #pragma unroll
  for (int l = 0; l < 4; l++) *(short8*)&Bs[0][lofs[l]] = *(const short8*)gB[l];
  __syncthreads();
  f32x4 acc[4][4] = {};
  for (int it = 0; it < NIT; it++) {
    int k0 = it * 32;
    int cur = it & 1;
    short8 nx[4];
    if (it + 1 < NIT) {
      #pragma unroll
      for (int l = 0; l < 4; l++) nx[l] = *(const short8*)(gB[l] + k0 + 32);
    }
    short8 a[4];
    #pragma unroll
    for (int mt = 0; mt < 4; mt++) a[mt] = *(const short8*)(ap[mt] + k0);
    #pragma unroll
    for (int tt = 0; tt < 4; tt++) {
      int col = w * 64 + tt * 16 + m;
      short8 bf = *(const short8*)&Bs[cur][col * 32 + kg * 8];
      #pragma unroll
      for (int mt = 0; mt < 4; mt++)
        acc[mt][tt] = __builtin_amdgcn_mfma_f32_16x16x32_bf16(a[mt], bf, acc[mt][tt], 0, 0, 0);
    }
    if (it + 1 < NIT) {
      #pragma unroll
      for (int l = 0; l < 4; l++) *(short8*)&Bs[cur ^ 1][lofs[l]] = nx[l];
    }
    __syncthreads();
  }
  #pragma unroll
  for (int mt = 0; mt < 4; mt++) {
    #pragma unroll
    for (int tt = 0; tt < 4; tt++) {
      int col = nz * 128 + w * 64 + tt * 16 + m;
      #pragma unroll
      for (int r = 0; r < 4; r++) {
        int row = mg * 64 + mt * 16 + kg * 4 + r;
        if (row < 216) wsumb[((size_t)b * 216 + row) * Cc + col] = f2bf(acc[mt][tt][r]);
      }
    }
  }
}

// ---------------- K13: attnout = Wv * wsum via MFMA ----------------
__global__ __launch_bounds__(256) void k_attnout_mfma(
    const unsigned short* __restrict__ wsumb, const unsigned short* __restrict__ wvb,
    unsigned short* __restrict__ aob) {
  int h = blockIdx.x, mt = blockIdx.y;
  int wid = threadIdx.x >> 6, lane = threadIdx.x & 63;
  int m = lane & 15, kg = lane >> 4;
  int row = mt * 16 + m;
  int b = row / NR, i = row % NR;
  const unsigned short* abase = wsumb + ((size_t)b * 216 + i * 12 + h) * Cc + kg * 8;
  const unsigned short* bbase = wvb + (size_t)(h * HD + wid * 16 + m) * Cc + kg * 8;
  f32x4 acc = {0, 0, 0, 0};
  for (int k0 = 0; k0 < Cc; k0 += 32) {
    short8 a = *(const short8*)(abase + k0);
    short8 bf = *(const short8*)(bbase + k0);
    acc = __builtin_amdgcn_mfma_f32_16x16x32_bf16(a, bf, acc, 0, 0, 0);
  }
  #pragma unroll
  for (int r = 0; r < 4; r++) {
    int orow = mt * 16 + kg * 4 + r;
    int ocol = h * HD + wid * 16 + m;
    aob[(size_t)orow * Cc + ocol] = f2bf(acc[r]);
  }
}

// ---------------- K14: proj via MFMA + bias + residual + scatter ----------
__global__ __launch_bounds__(256) void k_proj_mfma(
    const unsigned short* __restrict__ aob, const unsigned short* __restrict__ wpb,
    const float* __restrict__ bproj, const int* __restrict__ rowcat,
    const float* __restrict__ gen, const float* __restrict__ cls,
    const float* __restrict__ box, float* __restrict__ out) {
  int mt = blockIdx.x, ng = blockIdx.y;
  int wid = threadIdx.x >> 6, lane = threadIdx.x & 63;
  int nt = ng * 4 + wid;
  int m = lane & 15, kg = lane >> 4;
  const unsigned short* abase = aob + (size_t)(mt * 16 + m) * Cc + kg * 8;
  const unsigned short* bbase = wpb + (size_t)(nt * 16 + m) * Cc + kg * 8;
  f32x4 acc = {0, 0, 0, 0};
  for (int k0 = 0; k0 < Cc; k0 += 32) {
    short8 a = *(const short8*)(abase + k0);
    short8 bf = *(const short8*)(bbase + k0);
    acc = __builtin_amdgcn_mfma_f32_16x16x32_bf16(a, bf, acc, 0, 0, 0);
  }
  int c = nt * 16 + m;
  float bp = bproj[c];
  #pragma unroll
  for (int r = 0; r < 4; r++) {
    int bi = mt * 16 + kg * 4 + r;
    int b = bi / NR, i = bi % NR;
    int tok = rowcat[b * NR + i];
    const float* src = (tok == 0) ? cls + (size_t)b * Cc
                     : (tok == 1) ? box + (size_t)b * Cc
                                  : gen + ((size_t)b * NG + tok - 2) * Cc;
    float val = acc[r] + bp + src[c];
    float* dst;
    if (i == 0)       dst = out + ((size_t)b * 9 + 0) * Cc;
    else if (i == 1)  dst = out + (size_t)Bn * 9 * Cc + ((size_t)b * 9 + 0) * Cc;
    else if (i < 10)  dst = out + ((size_t)b * 9 + (i - 1)) * Cc;
    else              dst = out + (size_t)Bn * 9 * Cc + ((size_t)b * 9 + (i - 9)) * Cc;
    dst[c] = val;
  }
}

}  // namespace

extern "C" void kernel_launch(void* const* d_in, const int* in_sizes, int n_in,
                              void* d_out, int out_size, void* d_ws, size_t ws_size,
                              hipStream_t stream) {
  (void)in_sizes; (void)n_in; (void)out_size; (void)ws_size;
  const float* gen   = (const float*)d_in[0];
  const float* cls   = (const float*)d_in[1];
  const float* box   = (const float*)d_in[2];
  const float* wqkv  = (const float*)d_in[3];
  const float* wproj = (const float*)d_in[4];
  const float* bproj = (const float*)d_in[5];
  const float* gamma = (const float*)d_in[6];
  const float* beta  = (const float*)d_in[7];
  float* out = (float*)d_out;

  char* ws = (char*)d_ws;
  size_t off = 0;
  auto alloc = [&](size_t bytes) { void* p = ws + off; off += (bytes + 255) & ~(size_t)255; return p; };
  float* x             = (float*)alloc((size_t)Bn * Nn * Cc * 4);
  unsigned short* xbf  = (unsigned short*)alloc((size_t)Bn * NPK * Cc * 2);
  unsigned short* xT   = (unsigned short*)alloc((size_t)Bn * Cc * NPK * 2);
  unsigned short* qb   = (unsigned short*)alloc((size_t)256 * Cc * 2);
  unsigned short* u16b = (unsigned short*)alloc((size_t)Bn * 192 * Cc * 2);
  float* S             = (float*)alloc((size_t)Bn * 192 * NPK * 4);
  unsigned short* Pb   = (unsigned short*)alloc((size_t)Bn * 216 * NPK * 2);
  unsigned short* wsumb= (unsigned short*)alloc((size_t)Bn * 216 * Cc * 2);
  unsigned short* aob  = (unsigned short*)alloc((size_t)288 * Cc * 2);
  unsigned short* wqb  = (unsigned short*)alloc((size_t)Cc * Cc * 2);
  unsigned short* wvb  = (unsigned short*)alloc((size_t)Cc * Cc * 2);
  unsigned short* wpb  = (unsigned short*)alloc((size_t)Cc * Cc * 2);
  unsigned short* wkTb = (unsigned short*)alloc((size_t)Cc * Cc * 2);
  double* q01d         = (double*)alloc((size_t)Bn * 2 * Cc * 8);
  double* u01d         = (double*)alloc((size_t)Bn * 2 * Hh * Cc * 8);
  double* Ld           = (double*)alloc((size_t)Bn * 2 * Hh * Nn * 8);
  double* Ld01         = (double*)alloc((size_t)Bn * 2 * Hh * 2 * 8);
  float* Ldp           = (float*)alloc((size_t)NCH * Bn * 24 * 1024 * 4);
  int* rowcat          = (int*)alloc((size_t)Bn * NR * 4);

  k_ln<<<Bn * Nn + 96, 256, 0, stream>>>(gen, cls, box, gamma, beta, x, xbf);
  k_mega1<<<10320, 256, 0, stream>>>(xbf, xT, wqkv, wproj, wqb, wvb, wpb, wkTb, x, q01d);
  k_u01<<<dim3(Bn * 2 * Hh, 3), 256, 0, stream>>>(wqkv, q01d, u01d);
  k_mega2<<<1056, 256, 0, stream>>>(u01d, x, Ldp, Ld01);
  k_rsoftmax<<<Bn * 2 * Hh, 256, 0, stream>>>(Ldp, Ld01, Ld, Pb);
  k_rsroute<<<Bn, 256, 0, stream>>>(Ld, rowcat);
  k_qg_mfma<<<dim3(16, 12), 256, 0, stream>>>(xbf, wqb, rowcat, qb);
  k_ug_mfma<<<dim3(Hh, 16, 3), 256, 0, stream>>>(qb, wkTb, u16b);
  k_glogits_mfma<<<dim3(Bn, 3, 9), 128, 0, stream>>>(u16b, xbf, S);
  k_gsoftmax<<<Bn * 192, 256, 0, stream>>>(S, Pb);
  k_wsum_mfma<<<dim3(Bn, 4, 6), 128, 0, stream>>>(Pb, xT, wsumb);
  k_attnout_mfma<<<dim3(Hh, 18), 256, 0, stream>>>(wsumb, wvb, aob);
  k_proj_mfma<<<dim3(18, 12), 256, 0, stream>>>(aob, wpb, bproj, rowcat, gen, cls, box, out);
}